// Round 1
// baseline (709.296 us; speedup 1.0000x reference)
//
#include <hip/hip_runtime.h>
#include <hip/hip_bf16.h>
#include <math.h>

// Problem constants
#define LSEQ 4608     // 48 * 96
#define CDIM 640
#define DIN 1280
#define DSTATE 8
#define DTRANK 40
#define NCHUNK 48
#define CLEN 96
#define OUT_HALF 1474560  // 640*48*48

__device__ __forceinline__ float silu_f(float v){ return v / (1.f + __expf(-v)); }

// ---------------------------------------------------------------------------
// K0: gather x/y -> seq (L,640), LayerNorm -> xn (L,640). One block per row.
// ---------------------------------------------------------------------------
__global__ __launch_bounds__(256) void k_seq_ln(const float* __restrict__ x, const float* __restrict__ y,
        const float* __restrict__ g, const float* __restrict__ bta,
        float* __restrict__ seq, float* __restrict__ xn)
{
    int l = blockIdx.x;
    int tid = threadIdx.x;
    int h = l / 96, w2 = l - h*96;
    const float* src = (w2 < 48) ? x : y;
    int base = h*48 + (w2 < 48 ? w2 : w2 - 48);
    float v0 = src[(tid      )*2304 + base];
    float v1 = src[(tid + 256)*2304 + base];
    float v2 = (tid < 128) ? src[(tid + 512)*2304 + base] : 0.f;
    float s  = v0 + v1 + v2;
    float s2 = v0*v0 + v1*v1 + v2*v2;
    #pragma unroll
    for (int off = 32; off > 0; off >>= 1){
        s  += __shfl_down(s,  off, 64);
        s2 += __shfl_down(s2, off, 64);
    }
    __shared__ float red[2][4];
    int wid = tid >> 6;
    if ((tid & 63) == 0){ red[0][wid] = s; red[1][wid] = s2; }
    __syncthreads();
    float ts  = red[0][0] + red[0][1] + red[0][2] + red[0][3];
    float ts2 = red[1][0] + red[1][1] + red[1][2] + red[1][3];
    float mean = ts * (1.f/640.f);
    float var  = ts2 * (1.f/640.f) - mean*mean;
    float rs = rsqrtf(var + 1e-5f);
    int c = tid;
    seq[l*640 + c] = v0; xn[l*640 + c] = (v0 - mean)*rs*g[c] + bta[c];
    c = tid + 256;
    seq[l*640 + c] = v1; xn[l*640 + c] = (v1 - mean)*rs*g[c] + bta[c];
    if (tid < 128){
        c = tid + 512;
        seq[l*640 + c] = v2; xn[l*640 + c] = (v2 - mean)*rs*g[c] + bta[c];
    }
}

// ---------------------------------------------------------------------------
// Generic fp32 SIMT GEMM, 128x128 tile, BK=16, 256 threads, 8x8 per thread
// (split 2x2 of 4x4 micro-tiles). SCATTER=1: epilogue adds seq residual and
// scatters to the (640,48,96)->split output layout.
// ---------------------------------------------------------------------------
template<int SCATTER>
__global__ __launch_bounds__(256) void gemm128(const float* __restrict__ A, const float* __restrict__ B,
        float* __restrict__ C, const float* __restrict__ seq, float* __restrict__ outp,
        int M, int N, int K)
{
    __shared__ float As[16][132];
    __shared__ float Bs[16][132];
    int tid = threadIdx.x;
    int bn0 = blockIdx.x * 128;
    int bm0 = blockIdx.y * 128;
    int tx = tid & 15, ty = tid >> 4;
    float acc[2][2][4][4] = {};
    for (int k0 = 0; k0 < K; k0 += 16){
        #pragma unroll
        for (int i = 0; i < 2; ++i){
            int lin = tid + 256*i;          // 0..511
            int row = lin >> 2;             // 0..127
            int kq  = (lin & 3) << 2;       // {0,4,8,12}
            const float4 v = *(const float4*)&A[(bm0 + row)*K + k0 + kq];
            As[kq+0][row] = v.x; As[kq+1][row] = v.y; As[kq+2][row] = v.z; As[kq+3][row] = v.w;
        }
        #pragma unroll
        for (int i = 0; i < 2; ++i){
            int lin = tid + 256*i;
            int row = lin >> 5;             // 0..15
            int cq  = (lin & 31) << 2;      // 0..124
            *(float4*)&Bs[row][cq] = *(const float4*)&B[(k0 + row)*N + bn0 + cq];
        }
        __syncthreads();
        #pragma unroll
        for (int k = 0; k < 16; ++k){
            float4 a0 = *(const float4*)&As[k][ty*4];
            float4 a1 = *(const float4*)&As[k][64 + ty*4];
            float4 b0 = *(const float4*)&Bs[k][tx*4];
            float4 b1 = *(const float4*)&Bs[k][64 + tx*4];
            float av[2][4] = {{a0.x,a0.y,a0.z,a0.w},{a1.x,a1.y,a1.z,a1.w}};
            float bv[2][4] = {{b0.x,b0.y,b0.z,b0.w},{b1.x,b1.y,b1.z,b1.w}};
            #pragma unroll
            for (int ih = 0; ih < 2; ++ih)
            #pragma unroll
            for (int i = 0; i < 4; ++i)
            #pragma unroll
            for (int jh = 0; jh < 2; ++jh)
            #pragma unroll
            for (int j = 0; j < 4; ++j)
                acc[ih][jh][i][j] = fmaf(av[ih][i], bv[jh][j], acc[ih][jh][i][j]);
        }
        __syncthreads();
    }
    if (SCATTER == 0){
        #pragma unroll
        for (int ih = 0; ih < 2; ++ih)
        #pragma unroll
        for (int i = 0; i < 4; ++i){
            int row = bm0 + ih*64 + ty*4 + i;
            #pragma unroll
            for (int jh = 0; jh < 2; ++jh){
                float4 v = make_float4(acc[ih][jh][i][0], acc[ih][jh][i][1],
                                       acc[ih][jh][i][2], acc[ih][jh][i][3]);
                *(float4*)&C[row*N + bn0 + jh*64 + tx*4] = v;
            }
        }
    } else {
        #pragma unroll
        for (int ih = 0; ih < 2; ++ih)
        #pragma unroll
        for (int i = 0; i < 4; ++i){
            int row = bm0 + ih*64 + ty*4 + i;    // = l
            int hh = row / 96, w2 = row - hh*96;
            int obase = (w2 < 48) ? (hh*48 + w2) : (OUT_HALF + hh*48 + w2 - 48);
            #pragma unroll
            for (int jh = 0; jh < 2; ++jh)
            #pragma unroll
            for (int j = 0; j < 4; ++j){
                int col = bn0 + jh*64 + tx*4 + j;
                float v = acc[ih][jh][i][j] + seq[row*640 + col];
                outp[obase + col*2304] = v;
            }
        }
    }
}

// ---------------------------------------------------------------------------
// Depthwise causal conv (K=4, pad-left 3) over sequence dim + SiLU.
// xp = xz[:, :1280] (row stride 2560).
// ---------------------------------------------------------------------------
__global__ __launch_bounds__(256) void k_conv(const float* __restrict__ xz, const float* __restrict__ cw,
        float* __restrict__ xa)
{
    int gid = blockIdx.x*256 + threadIdx.x;      // < 4608*1280
    int l = gid / 1280, d = gid - l*1280;
    float4 w = *(const float4*)&cw[d*4];
    float acc = w.w * xz[l*2560 + d];
    if (l >= 1) acc = fmaf(w.z, xz[(l-1)*2560 + d], acc);
    if (l >= 2) acc = fmaf(w.y, xz[(l-2)*2560 + d], acc);
    if (l >= 3) acc = fmaf(w.x, xz[(l-3)*2560 + d], acc);
    xa[gid] = silu_f(acc);
}

// ---------------------------------------------------------------------------
// proj = xa @ W_xproj  (M=4608, K=1280, N=56). 4 rows per block.
// ---------------------------------------------------------------------------
__global__ __launch_bounds__(256) void k_xproj(const float* __restrict__ xa, const float* __restrict__ W,
        float* __restrict__ proj)
{
    __shared__ float xs[5120];
    int tid = threadIdx.x;
    int r0 = blockIdx.x * 4;
    #pragma unroll
    for (int i = 0; i < 20; ++i) xs[tid + 256*i] = xa[r0*1280 + tid + 256*i];
    __syncthreads();
    if (tid < 224){
        int r = tid / 56, n = tid - r*56;
        const float* xr = &xs[r*1280];
        float acc = 0.f;
        #pragma unroll 8
        for (int k = 0; k < 1280; ++k) acc = fmaf(xr[k], W[k*56 + n], acc);
        proj[(r0 + r)*56 + n] = acc;
    }
}

// ---------------------------------------------------------------------------
// dt = softplus(proj[:, :40] @ W_dt + dt_bias)  (M=4608, K=40, N=1280)
// ---------------------------------------------------------------------------
__global__ __launch_bounds__(256) void k_dt(const float* __restrict__ proj, const float* __restrict__ Wdt,
        const float* __restrict__ bias, float* __restrict__ dt)
{
    __shared__ float ps[16][40];
    int tid = threadIdx.x;
    int n = blockIdx.x*256 + tid;
    int r0 = blockIdx.y*16;
    for (int i = tid; i < 640; i += 256){
        int r = i / 40, k = i - r*40;
        ps[r][k] = proj[(r0 + r)*56 + k];
    }
    __syncthreads();
    float acc[16] = {};
    for (int k = 0; k < 40; ++k){
        float w = Wdt[k*1280 + n];
        #pragma unroll
        for (int r = 0; r < 16; ++r) acc[r] = fmaf(ps[r][k], w, acc[r]);
    }
    float bb = bias[n];
    #pragma unroll
    for (int r = 0; r < 16; ++r){
        float v = acc[r] + bb;
        float sp = (v > 20.f) ? v : log1pf(__expf(v));
        dt[(r0 + r)*1280 + n] = sp;
    }
}

// ---------------------------------------------------------------------------
// SSM chunked scan. 48 chunks of 96. h[l] = exp(dt*A)*h[l-1] + dt*xa*B[l].
// Pass1: per-chunk partial h (zero-init) + sum(dt) per chunk.
// Pass2: inter-chunk scan (uses prod exp(dt*A) = exp(A*sum dt)).
// Pass3: replay with true init, y = <h,C> + xa*Dp, gate with silu(z).
// ---------------------------------------------------------------------------
__global__ __launch_bounds__(256) void k_scan1(const float* __restrict__ dt, const float* __restrict__ xa,
        const float* __restrict__ proj, const float* __restrict__ A_log,
        float* __restrict__ Hc, float* __restrict__ Sdt)
{
    __shared__ float Bsh[CLEN*8];
    int tid = threadIdx.x;
    int c = blockIdx.x;
    int d = blockIdx.y*256 + tid;
    for (int i = tid; i < CLEN*8; i += 256){
        int ll = i >> 3, s = i & 7;
        Bsh[i] = proj[(c*CLEN + ll)*56 + 40 + s];
    }
    float As[8];
    #pragma unroll
    for (int s = 0; s < 8; ++s) As[s] = -__expf(A_log[d*8 + s]);
    __syncthreads();
    float h[8] = {};
    float sdt = 0.f;
    for (int ll = 0; ll < CLEN; ++ll){
        int l = c*CLEN + ll;
        float dtv = dt[l*1280 + d];
        float xav = xa[l*1280 + d];
        sdt += dtv;
        float dx = dtv * xav;
        #pragma unroll
        for (int s = 0; s < 8; ++s)
            h[s] = fmaf(__expf(dtv*As[s]), h[s], dx * Bsh[ll*8 + s]);
    }
    int base = (c*1280 + d)*8;
    #pragma unroll
    for (int s = 0; s < 8; ++s) Hc[base + s] = h[s];
    Sdt[c*1280 + d] = sdt;
}

__global__ __launch_bounds__(256) void k_scan2(const float* __restrict__ A_log, const float* __restrict__ Hc,
        const float* __restrict__ Sdt, float* __restrict__ Hinit)
{
    int d = blockIdx.x*256 + threadIdx.x;
    float As[8];
    #pragma unroll
    for (int s = 0; s < 8; ++s) As[s] = -__expf(A_log[d*8 + s]);
    float h[8] = {};
    for (int c = 0; c < NCHUNK; ++c){
        int base = (c*1280 + d)*8;
        #pragma unroll
        for (int s = 0; s < 8; ++s) Hinit[base + s] = h[s];
        float sdt = Sdt[c*1280 + d];
        #pragma unroll
        for (int s = 0; s < 8; ++s)
            h[s] = fmaf(__expf(sdt*As[s]), h[s], Hc[base + s]);
    }
}

__global__ __launch_bounds__(256) void k_scan3(const float* __restrict__ dt, const float* __restrict__ xa,
        const float* __restrict__ proj, const float* __restrict__ xz, const float* __restrict__ A_log,
        const float* __restrict__ Dp, const float* __restrict__ Hinit, float* __restrict__ yo)
{
    __shared__ float Bsh[CLEN*8];
    __shared__ float Csh[CLEN*8];
    int tid = threadIdx.x;
    int c = blockIdx.x;
    int d = blockIdx.y*256 + tid;
    for (int i = tid; i < CLEN*8; i += 256){
        int ll = i >> 3, s = i & 7;
        Bsh[i] = proj[(c*CLEN + ll)*56 + 40 + s];
        Csh[i] = proj[(c*CLEN + ll)*56 + 48 + s];
    }
    float As[8];
    #pragma unroll
    for (int s = 0; s < 8; ++s) As[s] = -__expf(A_log[d*8 + s]);
    float Dpv = Dp[d];
    __syncthreads();
    float h[8];
    int hbase = (c*1280 + d)*8;
    #pragma unroll
    for (int s = 0; s < 8; ++s) h[s] = Hinit[hbase + s];
    for (int ll = 0; ll < CLEN; ++ll){
        int l = c*CLEN + ll;
        float dtv = dt[l*1280 + d];
        float xav = xa[l*1280 + d];
        float dx = dtv * xav;
        float yv = 0.f;
        #pragma unroll
        for (int s = 0; s < 8; ++s){
            h[s] = fmaf(__expf(dtv*As[s]), h[s], dx * Bsh[ll*8 + s]);
            yv = fmaf(h[s], Csh[ll*8 + s], yv);
        }
        yv = fmaf(xav, Dpv, yv);
        float zv = xz[l*2560 + 1280 + d];
        yo[l*1280 + d] = yv * silu_f(zv);
    }
}

// ---------------------------------------------------------------------------
extern "C" void kernel_launch(void* const* d_in, const int* in_sizes, int n_in,
                              void* d_out, int out_size, void* d_ws, size_t ws_size,
                              hipStream_t stream) {
    const float* x       = (const float*)d_in[0];
    const float* y       = (const float*)d_in[1];
    const float* ln_g    = (const float*)d_in[2];
    const float* ln_b    = (const float*)d_in[3];
    const float* W_in    = (const float*)d_in[4];
    const float* conv_w  = (const float*)d_in[5];
    const float* W_xproj = (const float*)d_in[6];
    const float* W_dt    = (const float*)d_in[7];
    const float* dt_bias = (const float*)d_in[8];
    const float* A_log   = (const float*)d_in[9];
    const float* Dp      = (const float*)d_in[10];
    const float* W_out   = (const float*)d_in[11];
    float* out = (float*)d_out;
    float* w = (float*)d_ws;

    // workspace layout (floats)
    float* seq   = w;                 // 2,949,120
    float* xn    = w + 2949120;       // 2,949,120 (reused as yo after GEMM1)
    float* xz    = w + 5898240;       // 11,796,480
    float* xa    = w + 17694720;      // 5,898,240
    float* proj  = w + 23592960;      // 258,048
    float* dt    = w + 23851008;      // 5,898,240
    float* Hc    = w + 29749248;      // 491,520
    float* Sdt   = w + 30240768;      // 61,440
    float* Hinit = w + 30302208;      // 491,520  (total 30,793,728 floats = 123.2 MB)
    float* yo = xn;

    k_seq_ln<<<LSEQ, 256, 0, stream>>>(x, y, ln_g, ln_b, seq, xn);
    gemm128<0><<<dim3(20, 36), 256, 0, stream>>>(xn, W_in, xz, nullptr, nullptr, LSEQ, 2560, 640);
    k_conv<<<(LSEQ*DIN)/256, 256, 0, stream>>>(xz, conv_w, xa);
    k_xproj<<<LSEQ/4, 256, 0, stream>>>(xa, W_xproj, proj);
    k_dt<<<dim3(5, LSEQ/16), 256, 0, stream>>>(proj, W_dt, dt_bias, dt);
    k_scan1<<<dim3(NCHUNK, 5), 256, 0, stream>>>(dt, xa, proj, A_log, Hc, Sdt);
    k_scan2<<<5, 256, 0, stream>>>(A_log, Hc, Sdt, Hinit);
    k_scan3<<<dim3(NCHUNK, 5), 256, 0, stream>>>(dt, xa, proj, xz, A_log, Dp, Hinit, yo);
    gemm128<1><<<dim3(5, 36), 256, 0, stream>>>(yo, W_out, nullptr, seq, out, LSEQ, 640, 1280);
}

// Round 3
// 358.441 us; speedup vs baseline: 1.9788x; 1.9788x over previous
//
#include <hip/hip_runtime.h>
#include <hip/hip_bf16.h>
#include <math.h>

// Problem constants
#define LSEQ 4608     // 48 * 96
#define CDIM 640
#define DIN 1280
#define DSTATE 8
#define DTRANK 40
#define NCHUNK 48
#define CLEN 96
#define OUT_HALF 1474560  // 640*48*48

typedef __attribute__((ext_vector_type(8))) short short8v;   // 8 bf16 = 4 VGPRs
typedef __attribute__((ext_vector_type(4))) float f32x4;

__device__ __forceinline__ float silu_f(float v){ return v / (1.f + __expf(-v)); }

__device__ __forceinline__ void gload16(const void* g, void* l){
    __builtin_amdgcn_global_load_lds((const __attribute__((address_space(1))) void*)g,
                                     (__attribute__((address_space(3))) void*)l, 16, 0, 0);
}

// ---------------------------------------------------------------------------
// Transpose + fp32->bf16 cast: in (R x C) fp32 -> out (Cp x R) bf16, zero-pad
// rows C..Cp-1. Grid (Cp/32, R/32), block 256 (32x8).
// ---------------------------------------------------------------------------
__global__ __launch_bounds__(256) void k_transpose(const float* __restrict__ in,
        __hip_bfloat16* __restrict__ out, int R, int C, int Cp)
{
    __shared__ float t[32][33];
    int tid = threadIdx.x;
    int tx = tid & 31, ty = tid >> 5;
    int r0 = blockIdx.y*32, c0 = blockIdx.x*32;
    #pragma unroll
    for (int i = 0; i < 4; ++i){
        int r = r0 + ty + i*8, c = c0 + tx;
        t[ty + i*8][tx] = (c < C) ? in[r*C + c] : 0.f;
    }
    __syncthreads();
    #pragma unroll
    for (int i = 0; i < 4; ++i){
        int c = c0 + ty + i*8;
        out[c*R + r0 + tx] = __float2bfloat16(t[tx][ty + i*8]);
    }
}

// ---------------------------------------------------------------------------
// K0: gather x/y -> seq (L,640) fp32, LayerNorm -> xn (L,640) bf16.
// ---------------------------------------------------------------------------
__global__ __launch_bounds__(256) void k_seq_ln(const float* __restrict__ x, const float* __restrict__ y,
        const float* __restrict__ g, const float* __restrict__ bta,
        float* __restrict__ seq, __hip_bfloat16* __restrict__ xn)
{
    int l = blockIdx.x;
    int tid = threadIdx.x;
    int h = l / 96, w2 = l - h*96;
    const float* src = (w2 < 48) ? x : y;
    int base = h*48 + (w2 < 48 ? w2 : w2 - 48);
    float v0 = src[(tid      )*2304 + base];
    float v1 = src[(tid + 256)*2304 + base];
    float v2 = (tid < 128) ? src[(tid + 512)*2304 + base] : 0.f;
    float s  = v0 + v1 + v2;
    float s2 = v0*v0 + v1*v1 + v2*v2;
    #pragma unroll
    for (int off = 32; off > 0; off >>= 1){
        s  += __shfl_down(s,  off, 64);
        s2 += __shfl_down(s2, off, 64);
    }
    __shared__ float red[2][4];
    int wid = tid >> 6;
    if ((tid & 63) == 0){ red[0][wid] = s; red[1][wid] = s2; }
    __syncthreads();
    float ts  = red[0][0] + red[0][1] + red[0][2] + red[0][3];
    float ts2 = red[1][0] + red[1][1] + red[1][2] + red[1][3];
    float mean = ts * (1.f/640.f);
    float var  = ts2 * (1.f/640.f) - mean*mean;
    float rs = rsqrtf(var + 1e-5f);
    int c = tid;
    seq[l*640 + c] = v0; xn[l*640 + c] = __float2bfloat16((v0 - mean)*rs*g[c] + bta[c]);
    c = tid + 256;
    seq[l*640 + c] = v1; xn[l*640 + c] = __float2bfloat16((v1 - mean)*rs*g[c] + bta[c]);
    if (tid < 128){
        c = tid + 512;
        seq[l*640 + c] = v2; xn[l*640 + c] = __float2bfloat16((v2 - mean)*rs*g[c] + bta[c]);
    }
}

// ---------------------------------------------------------------------------
// MFMA bf16 GEMM, m97 structure: 128x128 tile, BK=32, 256 threads (4 waves,
// 2x2 wave grid, 64x64 per wave). A: MxK row-major bf16. Bt: NxK row-major
// bf16. C row-major fp32. SCATTER=1: add seq residual, scatter to output.
// M, N, K must be multiples of 128/128/32.
// ---------------------------------------------------------------------------
template<int SCATTER>
__global__ __launch_bounds__(256) void gemm_mfma(const __hip_bfloat16* __restrict__ A,
        const __hip_bfloat16* __restrict__ Bt, float* __restrict__ C,
        const float* __restrict__ seq, float* __restrict__ outp, int N, int K)
{
    __shared__ __align__(16) short As[128*32];
    __shared__ __align__(16) short Bs[128*32];
    int tid = threadIdx.x;
    int lane = tid & 63, wid = tid >> 6;
    int bn0 = blockIdx.x*128, bm0 = blockIdx.y*128;
    int wm = wid >> 1, wn = wid & 1;
    int fr = lane & 15, ko = (lane >> 4) << 3;
    f32x4 acc[4][4];
    #pragma unroll
    for (int m = 0; m < 4; ++m)
    #pragma unroll
    for (int n = 0; n < 4; ++n)
        acc[m][n] = (f32x4){0.f, 0.f, 0.f, 0.f};

    for (int k0 = 0; k0 < K; k0 += 32){
        #pragma unroll
        for (int i = 0; i < 2; ++i){
            int c = tid + 256*i;
            int row = c >> 2, kq = (c & 3) << 3;
            gload16(&A[(size_t)(bm0 + row)*K + k0 + kq], (char*)As + c*16);
            gload16(&Bt[(size_t)(bn0 + row)*K + k0 + kq], (char*)Bs + c*16);
        }
        __syncthreads();
        short8v a[4], b[4];
        #pragma unroll
        for (int m = 0; m < 4; ++m) a[m] = *(const short8v*)&As[(wm*64 + m*16 + fr)*32 + ko];
        #pragma unroll
        for (int n = 0; n < 4; ++n) b[n] = *(const short8v*)&Bs[(wn*64 + n*16 + fr)*32 + ko];
        #pragma unroll
        for (int m = 0; m < 4; ++m)
        #pragma unroll
        for (int n = 0; n < 4; ++n)
            acc[m][n] = __builtin_amdgcn_mfma_f32_16x16x32_bf16(a[m], b[n], acc[m][n], 0, 0, 0);
        __syncthreads();
    }

    int rq = (lane >> 4) * 4;
    if (SCATTER == 0){
        #pragma unroll
        for (int m = 0; m < 4; ++m){
            #pragma unroll
            for (int r = 0; r < 4; ++r){
                int row = bm0 + wm*64 + m*16 + rq + r;
                #pragma unroll
                for (int n = 0; n < 4; ++n){
                    int col = bn0 + wn*64 + n*16 + fr;
                    C[(size_t)row*N + col] = acc[m][n][r];
                }
            }
        }
    } else {
        #pragma unroll
        for (int m = 0; m < 4; ++m){
            #pragma unroll
            for (int r = 0; r < 4; ++r){
                int row = bm0 + wm*64 + m*16 + rq + r;   // = l
                int hh = row / 96, w2 = row - hh*96;
                int obase = (w2 < 48) ? (hh*48 + w2) : (OUT_HALF + hh*48 + w2 - 48);
                #pragma unroll
                for (int n = 0; n < 4; ++n){
                    int col = bn0 + wn*64 + n*16 + fr;
                    float v = acc[m][n][r] + seq[row*640 + col];
                    outp[obase + col*2304] = v;
                }
            }
        }
    }
}

// ---------------------------------------------------------------------------
// xproj via MFMA: M=4608, N=64 (56 padded), K=1280. Tile 128x64, BK=32,
// 4 waves as 4x1 (wave tile 32x64). proj output fp32 (L,56).
// ---------------------------------------------------------------------------
__global__ __launch_bounds__(256) void xproj_mfma(const __hip_bfloat16* __restrict__ A,
        const __hip_bfloat16* __restrict__ Bt, float* __restrict__ proj)
{
    __shared__ __align__(16) short As[128*32];
    __shared__ __align__(16) short Bs[64*32];
    int tid = threadIdx.x;
    int lane = tid & 63, wid = tid >> 6;
    int bm0 = blockIdx.x*128;
    int fr = lane & 15, ko = (lane >> 4) << 3;
    f32x4 acc[2][4];
    #pragma unroll
    for (int m = 0; m < 2; ++m)
    #pragma unroll
    for (int n = 0; n < 4; ++n)
        acc[m][n] = (f32x4){0.f, 0.f, 0.f, 0.f};

    for (int k0 = 0; k0 < 1280; k0 += 32){
        #pragma unroll
        for (int i = 0; i < 2; ++i){
            int c = tid + 256*i;
            int row = c >> 2, kq = (c & 3) << 3;
            gload16(&A[(size_t)(bm0 + row)*1280 + k0 + kq], (char*)As + c*16);
        }
        {
            int c = tid;
            int row = c >> 2, kq = (c & 3) << 3;
            gload16(&Bt[(size_t)row*1280 + k0 + kq], (char*)Bs + c*16);
        }
        __syncthreads();
        short8v a[2], b[4];
        #pragma unroll
        for (int m = 0; m < 2; ++m) a[m] = *(const short8v*)&As[(wid*32 + m*16 + fr)*32 + ko];
        #pragma unroll
        for (int n = 0; n < 4; ++n) b[n] = *(const short8v*)&Bs[(n*16 + fr)*32 + ko];
        #pragma unroll
        for (int m = 0; m < 2; ++m)
        #pragma unroll
        for (int n = 0; n < 4; ++n)
            acc[m][n] = __builtin_amdgcn_mfma_f32_16x16x32_bf16(a[m], b[n], acc[m][n], 0, 0, 0);
        __syncthreads();
    }
    int rq = (lane >> 4) * 4;
    #pragma unroll
    for (int m = 0; m < 2; ++m)
    #pragma unroll
    for (int r = 0; r < 4; ++r){
        int row = bm0 + wid*32 + m*16 + rq + r;
        #pragma unroll
        for (int n = 0; n < 4; ++n){
            int col = n*16 + fr;
            if (col < 56) proj[row*56 + col] = acc[m][n][r];
        }
    }
}

// ---------------------------------------------------------------------------
// Depthwise causal conv (K=4, pad-left 3) + SiLU. Writes fp32 + bf16.
// ---------------------------------------------------------------------------
__global__ __launch_bounds__(256) void k_conv(const float* __restrict__ xz, const float* __restrict__ cw,
        float* __restrict__ xa, __hip_bfloat16* __restrict__ xab)
{
    int gid = blockIdx.x*256 + threadIdx.x;      // < 4608*1280
    int l = gid / 1280, d = gid - l*1280;
    float4 w = *(const float4*)&cw[d*4];
    float acc = w.w * xz[l*2560 + d];
    if (l >= 1) acc = fmaf(w.z, xz[(l-1)*2560 + d], acc);
    if (l >= 2) acc = fmaf(w.y, xz[(l-2)*2560 + d], acc);
    if (l >= 3) acc = fmaf(w.x, xz[(l-3)*2560 + d], acc);
    float v = silu_f(acc);
    xa[gid] = v;
    xab[gid] = __float2bfloat16(v);
}

// ---------------------------------------------------------------------------
// dt = softplus(proj[:, :40] @ W_dt + dt_bias)  (M=4608, K=40, N=1280)
// ---------------------------------------------------------------------------
__global__ __launch_bounds__(256) void k_dt(const float* __restrict__ proj, const float* __restrict__ Wdt,
        const float* __restrict__ bias, float* __restrict__ dt)
{
    __shared__ float ps[16][40];
    int tid = threadIdx.x;
    int n = blockIdx.x*256 + tid;
    int r0 = blockIdx.y*16;
    for (int i = tid; i < 640; i += 256){
        int r = i / 40, k = i - r*40;
        ps[r][k] = proj[(r0 + r)*56 + k];
    }
    __syncthreads();
    float acc[16] = {};
    for (int k = 0; k < 40; ++k){
        float w = Wdt[k*1280 + n];
        #pragma unroll
        for (int r = 0; r < 16; ++r) acc[r] = fmaf(ps[r][k], w, acc[r]);
    }
    float bb = bias[n];
    #pragma unroll
    for (int r = 0; r < 16; ++r){
        float v = acc[r] + bb;
        float sp = (v > 20.f) ? v : log1pf(__expf(v));
        dt[(r0 + r)*1280 + n] = sp;
    }
}

// ---------------------------------------------------------------------------
// SSM chunked scan (48 chunks x 96).
// ---------------------------------------------------------------------------
__global__ __launch_bounds__(256) void k_scan1(const float* __restrict__ dt, const float* __restrict__ xa,
        const float* __restrict__ proj, const float* __restrict__ A_log,
        float* __restrict__ Hc, float* __restrict__ Sdt)
{
    __shared__ float Bsh[CLEN*8];
    int tid = threadIdx.x;
    int c = blockIdx.x;
    int d = blockIdx.y*256 + tid;
    for (int i = tid; i < CLEN*8; i += 256){
        int ll = i >> 3, s = i & 7;
        Bsh[i] = proj[(c*CLEN + ll)*56 + 40 + s];
    }
    float As[8];
    #pragma unroll
    for (int s = 0; s < 8; ++s) As[s] = -__expf(A_log[d*8 + s]);
    __syncthreads();
    float h[8] = {};
    float sdt = 0.f;
    for (int ll = 0; ll < CLEN; ++ll){
        int l = c*CLEN + ll;
        float dtv = dt[l*1280 + d];
        float xav = xa[l*1280 + d];
        sdt += dtv;
        float dx = dtv * xav;
        #pragma unroll
        for (int s = 0; s < 8; ++s)
            h[s] = fmaf(__expf(dtv*As[s]), h[s], dx * Bsh[ll*8 + s]);
    }
    int base = (c*1280 + d)*8;
    #pragma unroll
    for (int s = 0; s < 8; ++s) Hc[base + s] = h[s];
    Sdt[c*1280 + d] = sdt;
}

__global__ __launch_bounds__(256) void k_scan2(const float* __restrict__ A_log, const float* __restrict__ Hc,
        const float* __restrict__ Sdt, float* __restrict__ Hinit)
{
    int d = blockIdx.x*256 + threadIdx.x;
    float As[8];
    #pragma unroll
    for (int s = 0; s < 8; ++s) As[s] = -__expf(A_log[d*8 + s]);
    float h[8] = {};
    for (int c = 0; c < NCHUNK; ++c){
        int base = (c*1280 + d)*8;
        #pragma unroll
        for (int s = 0; s < 8; ++s) Hinit[base + s] = h[s];
        float sdt = Sdt[c*1280 + d];
        #pragma unroll
        for (int s = 0; s < 8; ++s)
            h[s] = fmaf(__expf(sdt*As[s]), h[s], Hc[base + s]);
    }
}

__global__ __launch_bounds__(256) void k_scan3(const float* __restrict__ dt, const float* __restrict__ xa,
        const float* __restrict__ proj, const float* __restrict__ xz, const float* __restrict__ A_log,
        const float* __restrict__ Dp, const float* __restrict__ Hinit, __hip_bfloat16* __restrict__ yo)
{
    __shared__ float Bsh[CLEN*8];
    __shared__ float Csh[CLEN*8];
    int tid = threadIdx.x;
    int c = blockIdx.x;
    int d = blockIdx.y*256 + tid;
    for (int i = tid; i < CLEN*8; i += 256){
        int ll = i >> 3, s = i & 7;
        Bsh[i] = proj[(c*CLEN + ll)*56 + 40 + s];
        Csh[i] = proj[(c*CLEN + ll)*56 + 48 + s];
    }
    float As[8];
    #pragma unroll
    for (int s = 0; s < 8; ++s) As[s] = -__expf(A_log[d*8 + s]);
    float Dpv = Dp[d];
    __syncthreads();
    float h[8];
    int hbase = (c*1280 + d)*8;
    #pragma unroll
    for (int s = 0; s < 8; ++s) h[s] = Hinit[hbase + s];
    for (int ll = 0; ll < CLEN; ++ll){
        int l = c*CLEN + ll;
        float dtv = dt[l*1280 + d];
        float xav = xa[l*1280 + d];
        float dx = dtv * xav;
        float yv = 0.f;
        #pragma unroll
        for (int s = 0; s < 8; ++s){
            h[s] = fmaf(__expf(dtv*As[s]), h[s], dx * Bsh[ll*8 + s]);
            yv = fmaf(h[s], Csh[ll*8 + s], yv);
        }
        yv = fmaf(xav, Dpv, yv);
        float zv = xz[l*2560 + 1280 + d];
        yo[l*1280 + d] = __float2bfloat16(yv * silu_f(zv));
    }
}

// ---------------------------------------------------------------------------
extern "C" void kernel_launch(void* const* d_in, const int* in_sizes, int n_in,
                              void* d_out, int out_size, void* d_ws, size_t ws_size,
                              hipStream_t stream) {
    const float* x       = (const float*)d_in[0];
    const float* y       = (const float*)d_in[1];
    const float* ln_g    = (const float*)d_in[2];
    const float* ln_b    = (const float*)d_in[3];
    const float* W_in    = (const float*)d_in[4];
    const float* conv_w  = (const float*)d_in[5];
    const float* W_xproj = (const float*)d_in[6];
    const float* W_dt    = (const float*)d_in[7];
    const float* dt_bias = (const float*)d_in[8];
    const float* A_log   = (const float*)d_in[9];
    const float* Dp      = (const float*)d_in[10];
    const float* W_out   = (const float*)d_in[11];
    float* out = (float*)d_out;
    char* w = (char*)d_ws;

    // workspace layout (bytes)
    float* seq   = (float*)(w);                      // 11,796,480
    float* xz    = (float*)(w + 11796480);           // 47,185,920
    float* xa    = (float*)(w + 58982400);           // 23,592,960
    float* proj  = (float*)(w + 82575360);           //  1,032,192
    float* dt    = (float*)(w + 83607552);           // 23,592,960
    float* Hc    = (float*)(w + 107200512);          //  1,966,080
    float* Sdt   = (float*)(w + 109166592);          //    245,760
    float* Hinit = (float*)(w + 109412352);          //  1,966,080
    __hip_bfloat16* xnb   = (__hip_bfloat16*)(w + 111378432);  //  5,898,240
    __hip_bfloat16* xab   = (__hip_bfloat16*)(w + 117276672);  // 11,796,480
    __hip_bfloat16* yob   = (__hip_bfloat16*)(w + 129073152);  // 11,796,480
    __hip_bfloat16* WtIn  = (__hip_bfloat16*)(w + 140869632);  //  3,276,800
    __hip_bfloat16* WtOut = (__hip_bfloat16*)(w + 144146432);  //  1,638,400
    __hip_bfloat16* WtXp  = (__hip_bfloat16*)(w + 145784832);  //    163,840  (total ~145.9 MB)

    // Per-call weight transposes (inputs are restored each launch)
    k_transpose<<<dim3(80, 20), 256, 0, stream>>>(W_in,    WtIn,  640, 2560, 2560);
    k_transpose<<<dim3(20, 40), 256, 0, stream>>>(W_out,   WtOut, 1280, 640, 640);
    k_transpose<<<dim3(2,  40), 256, 0, stream>>>(W_xproj, WtXp,  1280, 56,  64);

    k_seq_ln<<<LSEQ, 256, 0, stream>>>(x, y, ln_g, ln_b, seq, xnb);
    gemm_mfma<0><<<dim3(20, 36), 256, 0, stream>>>(xnb, WtIn, xz, nullptr, nullptr, 2560, 640);
    k_conv<<<(LSEQ*DIN)/256, 256, 0, stream>>>(xz, conv_w, xa, xab);
    xproj_mfma<<<36, 256, 0, stream>>>(xab, WtXp, proj);
    k_dt<<<dim3(5, LSEQ/16), 256, 0, stream>>>(proj, W_dt, dt_bias, dt);
    k_scan1<<<dim3(NCHUNK, 5), 256, 0, stream>>>(dt, xa, proj, A_log, Hc, Sdt);
    k_scan2<<<5, 256, 0, stream>>>(A_log, Hc, Sdt, Hinit);
    k_scan3<<<dim3(NCHUNK, 5), 256, 0, stream>>>(dt, xa, proj, xz, A_log, Dp, Hinit, yob);
    gemm_mfma<1><<<dim3(5, 36), 256, 0, stream>>>(yob, WtOut, nullptr, seq, out, 640, 1280);
}

// Round 4
// 346.673 us; speedup vs baseline: 2.0460x; 1.0339x over previous
//
#include <hip/hip_runtime.h>
#include <hip/hip_bf16.h>
#include <math.h>

// Problem constants
#define LSEQ 4608     // 48 * 96
#define CDIM 640
#define DIN 1280
#define DSTATE 8
#define DTRANK 40
#define NCHUNK 48
#define CLEN 96
#define OUT_HALF 1474560  // 640*48*48

typedef __attribute__((ext_vector_type(8))) short short8v;   // 8 bf16 = 4 VGPRs
typedef __attribute__((ext_vector_type(4))) float f32x4;

__device__ __forceinline__ float silu_f(float v){ return v / (1.f + __expf(-v)); }

__device__ __forceinline__ void gload16(const void* g, void* l){
    __builtin_amdgcn_global_load_lds((const __attribute__((address_space(1))) void*)g,
                                     (__attribute__((address_space(3))) void*)l, 16, 0, 0);
}

// ---------------------------------------------------------------------------
// Pad-transpose + fp32->bf16: in (R x C) fp32 -> out (Cp x Rp) bf16.
// Zero-pads c in [C,Cp) and r in [R,Rp). Grid (Cp/32, Rp/32), block 256.
// ---------------------------------------------------------------------------
__global__ __launch_bounds__(256) void k_transpose(const float* __restrict__ in,
        __hip_bfloat16* __restrict__ out, int R, int C, int Cp, int Rp)
{
    __shared__ float t[32][33];
    int tid = threadIdx.x;
    int tx = tid & 31, ty = tid >> 5;
    int r0 = blockIdx.y*32, c0 = blockIdx.x*32;
    #pragma unroll
    for (int i = 0; i < 4; ++i){
        int r = r0 + ty + i*8, c = c0 + tx;
        t[ty + i*8][tx] = (r < R && c < C) ? in[(size_t)r*C + c] : 0.f;
    }
    __syncthreads();
    #pragma unroll
    for (int i = 0; i < 4; ++i){
        int c = c0 + ty + i*8;
        out[(size_t)c*Rp + r0 + tx] = __float2bfloat16(t[tx][ty + i*8]);
    }
}

// ---------------------------------------------------------------------------
// Gather/transpose x,y (C,48,48 each) -> seq (L=4608, 640) fp32.
// Both global sides coalesced via 32x32 LDS tile. Grid (144, 20).
// ---------------------------------------------------------------------------
__global__ __launch_bounds__(256) void k_gather(const float* __restrict__ x,
        const float* __restrict__ y, float* __restrict__ seq)
{
    __shared__ float t[32][33];
    int tid = threadIdx.x;
    int tx = tid & 31, ty = tid >> 5;
    int l0 = blockIdx.x*32, c0 = blockIdx.y*32;
    int l = l0 + tx;
    int h = l / 96, w2 = l - h*96;
    const float* src = (w2 < 48) ? x : y;
    int col = h*48 + (w2 < 48 ? w2 : w2 - 48);
    #pragma unroll
    for (int i = 0; i < 4; ++i)
        t[tx][ty + i*8] = src[(size_t)(c0 + ty + i*8)*2304 + col];
    __syncthreads();
    #pragma unroll
    for (int i = 0; i < 4; ++i){
        int l2 = l0 + ty + i*8;
        seq[(size_t)l2*640 + c0 + tx] = t[ty + i*8][tx];
    }
}

// ---------------------------------------------------------------------------
// Row LayerNorm: seq (L,640) fp32 -> xn (L,640) bf16. 1 wave per row.
// ---------------------------------------------------------------------------
__global__ __launch_bounds__(64) void k_ln(const float* __restrict__ seq,
        const float* __restrict__ g, const float* __restrict__ bta,
        __hip_bfloat16* __restrict__ xn)
{
    int l = blockIdx.x;
    int lane = threadIdx.x;
    const float* row = seq + (size_t)l*640;
    float2 v[5];
    float s = 0.f, s2 = 0.f;
    #pragma unroll
    for (int j = 0; j < 5; ++j){
        v[j] = *(const float2*)&row[j*128 + lane*2];
        s  += v[j].x + v[j].y;
        s2 += v[j].x*v[j].x + v[j].y*v[j].y;
    }
    #pragma unroll
    for (int off = 32; off > 0; off >>= 1){
        s  += __shfl_xor(s,  off, 64);
        s2 += __shfl_xor(s2, off, 64);
    }
    float mean = s * (1.f/640.f);
    float rs = rsqrtf(s2 * (1.f/640.f) - mean*mean + 1e-5f);
    #pragma unroll
    for (int j = 0; j < 5; ++j){
        int c = j*128 + lane*2;
        float2 gg = *(const float2*)&g[c];
        float2 bb = *(const float2*)&bta[c];
        __hip_bfloat162 ob;
        ob.x = __float2bfloat16((v[j].x - mean)*rs*gg.x + bb.x);
        ob.y = __float2bfloat16((v[j].y - mean)*rs*gg.y + bb.y);
        *(__hip_bfloat162*)&xn[(size_t)l*640 + c] = ob;
    }
}

// ---------------------------------------------------------------------------
// MFMA bf16 GEMM, 128xBN tile, BK=32, 256 threads (4 waves, 2x2 wave grid,
// wave tile 64 x BN/2). A: MxK row-major bf16. Bt: NxK row-major bf16.
// EPI=0: C fp32 store. EPI=1: +aux(seq) residual, scatter to output layout.
// EPI=2: softplus(acc + aux[col]) -> C (dt).
// ---------------------------------------------------------------------------
template<int EPI, int BN>
__global__ __launch_bounds__(256) void gemm_mfma(const __hip_bfloat16* __restrict__ A,
        const __hip_bfloat16* __restrict__ Bt, float* __restrict__ C,
        const float* __restrict__ aux, float* __restrict__ outp, int N, int K)
{
    constexpr int NF = BN/32;        // b-frags per wave
    __shared__ __align__(16) short As[128*32];
    __shared__ __align__(16) short Bs[BN*32];
    int tid = threadIdx.x;
    int lane = tid & 63, wid = tid >> 6;
    int bn0 = blockIdx.x*BN, bm0 = blockIdx.y*128;
    int wm = wid >> 1, wn = wid & 1;
    int fr = lane & 15, ko = (lane >> 4) << 3;
    f32x4 acc[4][NF];
    #pragma unroll
    for (int m = 0; m < 4; ++m)
    #pragma unroll
    for (int n = 0; n < NF; ++n)
        acc[m][n] = (f32x4){0.f, 0.f, 0.f, 0.f};

    for (int k0 = 0; k0 < K; k0 += 32){
        #pragma unroll
        for (int i = 0; i < 2; ++i){
            int c = tid + 256*i;
            int row = c >> 2, kq = (c & 3) << 3;
            gload16(&A[(size_t)(bm0 + row)*K + k0 + kq], (char*)As + c*16);
        }
        #pragma unroll
        for (int i = 0; i < BN/64; ++i){
            int c = tid + 256*i;
            int row = c >> 2, kq = (c & 3) << 3;
            gload16(&Bt[(size_t)(bn0 + row)*K + k0 + kq], (char*)Bs + c*16);
        }
        __syncthreads();
        short8v a[4], b[NF];
        #pragma unroll
        for (int m = 0; m < 4; ++m) a[m] = *(const short8v*)&As[(wm*64 + m*16 + fr)*32 + ko];
        #pragma unroll
        for (int n = 0; n < NF; ++n) b[n] = *(const short8v*)&Bs[(wn*(BN/2) + n*16 + fr)*32 + ko];
        #pragma unroll
        for (int m = 0; m < 4; ++m)
        #pragma unroll
        for (int n = 0; n < NF; ++n)
            acc[m][n] = __builtin_amdgcn_mfma_f32_16x16x32_bf16(a[m], b[n], acc[m][n], 0, 0, 0);
        __syncthreads();
    }

    int rq = (lane >> 4) * 4;
    #pragma unroll
    for (int m = 0; m < 4; ++m){
        #pragma unroll
        for (int r = 0; r < 4; ++r){
            int row = bm0 + wm*64 + m*16 + rq + r;
            if (EPI == 1){
                int hh = row / 96, w2 = row - hh*96;
                int obase = (w2 < 48) ? (hh*48 + w2) : (OUT_HALF + hh*48 + w2 - 48);
                #pragma unroll
                for (int n = 0; n < NF; ++n){
                    int col = bn0 + wn*(BN/2) + n*16 + fr;
                    float v = acc[m][n][r] + aux[(size_t)row*N + col];
                    outp[obase + (size_t)col*2304] = v;
                }
            } else {
                #pragma unroll
                for (int n = 0; n < NF; ++n){
                    int col = bn0 + wn*(BN/2) + n*16 + fr;
                    float v = acc[m][n][r];
                    if (EPI == 2){
                        v += aux[col];
                        v = (v > 20.f) ? v : log1pf(__expf(v));
                    }
                    C[(size_t)row*N + col] = v;
                }
            }
        }
    }
}

// ---------------------------------------------------------------------------
// xproj via MFMA: M=4608, N=64 (56 padded), K=1280. Tile 128x64, 4 waves
// as 4x1 (wave tile 32x64). Writes proj fp32 (L,56) and projb bf16 (L,64)
// with cols >= 40 zeroed (dt-GEMM A-operand).
// ---------------------------------------------------------------------------
__global__ __launch_bounds__(256) void xproj_mfma(const __hip_bfloat16* __restrict__ A,
        const __hip_bfloat16* __restrict__ Bt, float* __restrict__ proj,
        __hip_bfloat16* __restrict__ projb)
{
    __shared__ __align__(16) short As[128*32];
    __shared__ __align__(16) short Bs[64*32];
    int tid = threadIdx.x;
    int lane = tid & 63, wid = tid >> 6;
    int bm0 = blockIdx.x*128;
    int fr = lane & 15, ko = (lane >> 4) << 3;
    f32x4 acc[2][4];
    #pragma unroll
    for (int m = 0; m < 2; ++m)
    #pragma unroll
    for (int n = 0; n < 4; ++n)
        acc[m][n] = (f32x4){0.f, 0.f, 0.f, 0.f};

    for (int k0 = 0; k0 < 1280; k0 += 32){
        #pragma unroll
        for (int i = 0; i < 2; ++i){
            int c = tid + 256*i;
            int row = c >> 2, kq = (c & 3) << 3;
            gload16(&A[(size_t)(bm0 + row)*1280 + k0 + kq], (char*)As + c*16);
        }
        {
            int c = tid;
            int row = c >> 2, kq = (c & 3) << 3;
            gload16(&Bt[(size_t)row*1280 + k0 + kq], (char*)Bs + c*16);
        }
        __syncthreads();
        short8v a[2], b[4];
        #pragma unroll
        for (int m = 0; m < 2; ++m) a[m] = *(const short8v*)&As[(wid*32 + m*16 + fr)*32 + ko];
        #pragma unroll
        for (int n = 0; n < 4; ++n) b[n] = *(const short8v*)&Bs[(n*16 + fr)*32 + ko];
        #pragma unroll
        for (int m = 0; m < 2; ++m)
        #pragma unroll
        for (int n = 0; n < 4; ++n)
            acc[m][n] = __builtin_amdgcn_mfma_f32_16x16x32_bf16(a[m], b[n], acc[m][n], 0, 0, 0);
        __syncthreads();
    }
    int rq = (lane >> 4) * 4;
    #pragma unroll
    for (int m = 0; m < 2; ++m)
    #pragma unroll
    for (int r = 0; r < 4; ++r){
        int row = bm0 + wid*32 + m*16 + rq + r;
        #pragma unroll
        for (int n = 0; n < 4; ++n){
            int col = n*16 + fr;
            float v = acc[m][n][r];
            if (col < 56) proj[row*56 + col] = v;
            projb[row*64 + col] = __float2bfloat16(col < 40 ? v : 0.f);
        }
    }
}

// ---------------------------------------------------------------------------
// Depthwise causal conv (K=4, pad-left 3) + SiLU. Writes fp32 + bf16.
// ---------------------------------------------------------------------------
__global__ __launch_bounds__(256) void k_conv(const float* __restrict__ xz, const float* __restrict__ cw,
        float* __restrict__ xa, __hip_bfloat16* __restrict__ xab)
{
    int gid = blockIdx.x*256 + threadIdx.x;      // < 4608*1280
    int l = gid / 1280, d = gid - l*1280;
    float4 w = *(const float4*)&cw[d*4];
    float acc = w.w * xz[l*2560 + d];
    if (l >= 1) acc = fmaf(w.z, xz[(l-1)*2560 + d], acc);
    if (l >= 2) acc = fmaf(w.y, xz[(l-2)*2560 + d], acc);
    if (l >= 3) acc = fmaf(w.x, xz[(l-3)*2560 + d], acc);
    float v = silu_f(acc);
    xa[gid] = v;
    xab[gid] = __float2bfloat16(v);
}

// ---------------------------------------------------------------------------
// SSM chunked scan (48 chunks x 96).
// ---------------------------------------------------------------------------
__global__ __launch_bounds__(256) void k_scan1(const float* __restrict__ dt, const float* __restrict__ xa,
        const float* __restrict__ proj, const float* __restrict__ A_log,
        float* __restrict__ Hc, float* __restrict__ Sdt)
{
    __shared__ float Bsh[CLEN*8];
    int tid = threadIdx.x;
    int c = blockIdx.x;
    int d = blockIdx.y*256 + tid;
    for (int i = tid; i < CLEN*8; i += 256){
        int ll = i >> 3, s = i & 7;
        Bsh[i] = proj[(c*CLEN + ll)*56 + 40 + s];
    }
    float As[8];
    #pragma unroll
    for (int s = 0; s < 8; ++s) As[s] = -__expf(A_log[d*8 + s]);
    __syncthreads();
    float h[8] = {};
    float sdt = 0.f;
    for (int ll = 0; ll < CLEN; ++ll){
        int l = c*CLEN + ll;
        float dtv = dt[l*1280 + d];
        float xav = xa[l*1280 + d];
        sdt += dtv;
        float dx = dtv * xav;
        #pragma unroll
        for (int s = 0; s < 8; ++s)
            h[s] = fmaf(__expf(dtv*As[s]), h[s], dx * Bsh[ll*8 + s]);
    }
    int base = (c*1280 + d)*8;
    #pragma unroll
    for (int s = 0; s < 8; ++s) Hc[base + s] = h[s];
    Sdt[c*1280 + d] = sdt;
}

__global__ __launch_bounds__(256) void k_scan2(const float* __restrict__ A_log, const float* __restrict__ Hc,
        const float* __restrict__ Sdt, float* __restrict__ Hinit)
{
    int d = blockIdx.x*256 + threadIdx.x;
    float As[8];
    #pragma unroll
    for (int s = 0; s < 8; ++s) As[s] = -__expf(A_log[d*8 + s]);
    float h[8] = {};
    for (int c = 0; c < NCHUNK; ++c){
        int base = (c*1280 + d)*8;
        #pragma unroll
        for (int s = 0; s < 8; ++s) Hinit[base + s] = h[s];
        float sdt = Sdt[c*1280 + d];
        #pragma unroll
        for (int s = 0; s < 8; ++s)
            h[s] = fmaf(__expf(sdt*As[s]), h[s], Hc[base + s]);
    }
}

__global__ __launch_bounds__(256) void k_scan3(const float* __restrict__ dt, const float* __restrict__ xa,
        const float* __restrict__ proj, const float* __restrict__ xz, const float* __restrict__ A_log,
        const float* __restrict__ Dp, const float* __restrict__ Hinit, __hip_bfloat16* __restrict__ yo)
{
    __shared__ float Bsh[CLEN*8];
    __shared__ float Csh[CLEN*8];
    int tid = threadIdx.x;
    int c = blockIdx.x;
    int d = blockIdx.y*256 + tid;
    for (int i = tid; i < CLEN*8; i += 256){
        int ll = i >> 3, s = i & 7;
        Bsh[i] = proj[(c*CLEN + ll)*56 + 40 + s];
        Csh[i] = proj[(c*CLEN + ll)*56 + 48 + s];
    }
    float As[8];
    #pragma unroll
    for (int s = 0; s < 8; ++s) As[s] = -__expf(A_log[d*8 + s]);
    float Dpv = Dp[d];
    __syncthreads();
    float h[8];
    int hbase = (c*1280 + d)*8;
    #pragma unroll
    for (int s = 0; s < 8; ++s) h[s] = Hinit[hbase + s];
    for (int ll = 0; ll < CLEN; ++ll){
        int l = c*CLEN + ll;
        float dtv = dt[l*1280 + d];
        float xav = xa[l*1280 + d];
        float dx = dtv * xav;
        float yv = 0.f;
        #pragma unroll
        for (int s = 0; s < 8; ++s){
            h[s] = fmaf(__expf(dtv*As[s]), h[s], dx * Bsh[ll*8 + s]);
            yv = fmaf(h[s], Csh[ll*8 + s], yv);
        }
        yv = fmaf(xav, Dpv, yv);
        float zv = xz[l*2560 + 1280 + d];
        yo[l*1280 + d] = __float2bfloat16(yv * silu_f(zv));
    }
}

// ---------------------------------------------------------------------------
extern "C" void kernel_launch(void* const* d_in, const int* in_sizes, int n_in,
                              void* d_out, int out_size, void* d_ws, size_t ws_size,
                              hipStream_t stream) {
    const float* x       = (const float*)d_in[0];
    const float* y       = (const float*)d_in[1];
    const float* ln_g    = (const float*)d_in[2];
    const float* ln_b    = (const float*)d_in[3];
    const float* W_in    = (const float*)d_in[4];
    const float* conv_w  = (const float*)d_in[5];
    const float* W_xproj = (const float*)d_in[6];
    const float* W_dt    = (const float*)d_in[7];
    const float* dt_bias = (const float*)d_in[8];
    const float* A_log   = (const float*)d_in[9];
    const float* Dp      = (const float*)d_in[10];
    const float* W_out   = (const float*)d_in[11];
    float* out = (float*)d_out;
    char* w = (char*)d_ws;

    // workspace layout (bytes)
    float* seq   = (float*)(w);                      // 11,796,480
    float* xz    = (float*)(w + 11796480);           // 47,185,920
    float* xa    = (float*)(w + 58982400);           // 23,592,960
    float* proj  = (float*)(w + 82575360);           //  1,032,192
    float* dt    = (float*)(w + 83607552);           // 23,592,960
    float* Hc    = (float*)(w + 107200512);          //  1,966,080
    float* Sdt   = (float*)(w + 109166592);          //    245,760
    float* Hinit = (float*)(w + 109412352);          //  1,966,080
    __hip_bfloat16* xnb   = (__hip_bfloat16*)(w + 111378432);  //  5,898,240
    __hip_bfloat16* xab   = (__hip_bfloat16*)(w + 117276672);  // 11,796,480
    __hip_bfloat16* yob   = (__hip_bfloat16*)(w + 129073152);  // 11,796,480
    __hip_bfloat16* WtIn  = (__hip_bfloat16*)(w + 140869632);  //  3,276,800
    __hip_bfloat16* WtOut = (__hip_bfloat16*)(w + 144146432);  //  1,638,400
    __hip_bfloat16* WtXp  = (__hip_bfloat16*)(w + 145784832);  //    163,840
    __hip_bfloat16* projb = (__hip_bfloat16*)(w + 145948672);  //    589,824
    __hip_bfloat16* Wdtb  = (__hip_bfloat16*)(w + 146538496);  //    163,840  (total ~146.7 MB)

    // Per-call weight transposes (inputs are restored each launch)
    k_transpose<<<dim3(80, 20), 256, 0, stream>>>(W_in,    WtIn,  640, 2560, 2560, 640);
    k_transpose<<<dim3(20, 40), 256, 0, stream>>>(W_out,   WtOut, 1280, 640, 640, 1280);
    k_transpose<<<dim3(2,  40), 256, 0, stream>>>(W_xproj, WtXp,  1280, 56,  64, 1280);
    k_transpose<<<dim3(40,  2), 256, 0, stream>>>(W_dt,    Wdtb,  40, 1280, 1280, 64);

    k_gather<<<dim3(144, 20), 256, 0, stream>>>(x, y, seq);
    k_ln<<<LSEQ, 64, 0, stream>>>(seq, ln_g, ln_b, xnb);
    gemm_mfma<0,128><<<dim3(20, 36), 256, 0, stream>>>(xnb, WtIn, xz, nullptr, nullptr, 2560, 640);
    k_conv<<<(LSEQ*DIN)/256, 256, 0, stream>>>(xz, conv_w, xa, xab);
    xproj_mfma<<<36, 256, 0, stream>>>(xab, WtXp, proj, projb);
    gemm_mfma<2,128><<<dim3(10, 36), 256, 0, stream>>>(projb, Wdtb, dt, dt_bias, nullptr, 1280, 64);
    k_scan1<<<dim3(NCHUNK, 5), 256, 0, stream>>>(dt, xa, proj, A_log, Hc, Sdt);
    k_scan2<<<5, 256, 0, stream>>>(A_log, Hc, Sdt, Hinit);
    k_scan3<<<dim3(NCHUNK, 5), 256, 0, stream>>>(dt, xa, proj, xz, A_log, Dp, Hinit, yob);
    gemm_mfma<1,64><<<dim3(10, 36), 256, 0, stream>>>(yob, WtOut, nullptr, seq, out, 640, 1280);
}

// Round 5
// 323.491 us; speedup vs baseline: 2.1926x; 1.0717x over previous
//
#include <hip/hip_runtime.h>
#include <hip/hip_bf16.h>
#include <math.h>

// Problem constants
#define LSEQ 4608     // 48 * 96
#define CDIM 640
#define DIN 1280
#define DSTATE 8
#define DTRANK 40
#define NCHUNK 192
#define CLEN 24
#define OUT_HALF 1474560  // 640*48*48

typedef __attribute__((ext_vector_type(8))) short short8v;   // 8 bf16 = 4 VGPRs
typedef __attribute__((ext_vector_type(4))) float f32x4;

__device__ __forceinline__ float silu_f(float v){ return v / (1.f + __expf(-v)); }

__device__ __forceinline__ void gload16(const void* g, void* l){
    __builtin_amdgcn_global_load_lds((const __attribute__((address_space(1))) void*)g,
                                     (__attribute__((address_space(3))) void*)l, 16, 0, 0);
}

// ---------------------------------------------------------------------------
// Pad-transpose + fp32->bf16: in (R x C) fp32 -> out (Cp x Rp) bf16.
// Zero-pads c in [C,Cp) and r in [R,Rp). Grid (Cp/32, Rp/32), block 256.
// ---------------------------------------------------------------------------
__global__ __launch_bounds__(256) void k_transpose(const float* __restrict__ in,
        __hip_bfloat16* __restrict__ out, int R, int C, int Cp, int Rp)
{
    __shared__ float t[32][33];
    int tid = threadIdx.x;
    int tx = tid & 31, ty = tid >> 5;
    int r0 = blockIdx.y*32, c0 = blockIdx.x*32;
    #pragma unroll
    for (int i = 0; i < 4; ++i){
        int r = r0 + ty + i*8, c = c0 + tx;
        t[ty + i*8][tx] = (r < R && c < C) ? in[(size_t)r*C + c] : 0.f;
    }
    __syncthreads();
    #pragma unroll
    for (int i = 0; i < 4; ++i){
        int c = c0 + ty + i*8;
        out[(size_t)c*Rp + r0 + tx] = __float2bfloat16(t[tx][ty + i*8]);
    }
}

// ---------------------------------------------------------------------------
// Gather/transpose x,y (C,48,48 each) -> seq (L=4608, 640) fp32.
// Both global sides coalesced via 32x32 LDS tile. Grid (144, 20).
// ---------------------------------------------------------------------------
__global__ __launch_bounds__(256) void k_gather(const float* __restrict__ x,
        const float* __restrict__ y, float* __restrict__ seq)
{
    __shared__ float t[32][33];
    int tid = threadIdx.x;
    int tx = tid & 31, ty = tid >> 5;
    int l0 = blockIdx.x*32, c0 = blockIdx.y*32;
    int l = l0 + tx;
    int h = l / 96, w2 = l - h*96;
    const float* src = (w2 < 48) ? x : y;
    int col = h*48 + (w2 < 48 ? w2 : w2 - 48);
    #pragma unroll
    for (int i = 0; i < 4; ++i)
        t[tx][ty + i*8] = src[(size_t)(c0 + ty + i*8)*2304 + col];
    __syncthreads();
    #pragma unroll
    for (int i = 0; i < 4; ++i){
        int l2 = l0 + ty + i*8;
        seq[(size_t)l2*640 + c0 + tx] = t[ty + i*8][tx];
    }
}

// ---------------------------------------------------------------------------
// Row LayerNorm: seq (L,640) fp32 -> xn (L,640) bf16. 1 wave per row.
// ---------------------------------------------------------------------------
__global__ __launch_bounds__(64) void k_ln(const float* __restrict__ seq,
        const float* __restrict__ g, const float* __restrict__ bta,
        __hip_bfloat16* __restrict__ xn)
{
    int l = blockIdx.x;
    int lane = threadIdx.x;
    const float* row = seq + (size_t)l*640;
    float2 v[5];
    float s = 0.f, s2 = 0.f;
    #pragma unroll
    for (int j = 0; j < 5; ++j){
        v[j] = *(const float2*)&row[j*128 + lane*2];
        s  += v[j].x + v[j].y;
        s2 += v[j].x*v[j].x + v[j].y*v[j].y;
    }
    #pragma unroll
    for (int off = 32; off > 0; off >>= 1){
        s  += __shfl_xor(s,  off, 64);
        s2 += __shfl_xor(s2, off, 64);
    }
    float mean = s * (1.f/640.f);
    float rs = rsqrtf(s2 * (1.f/640.f) - mean*mean + 1e-5f);
    #pragma unroll
    for (int j = 0; j < 5; ++j){
        int c = j*128 + lane*2;
        float2 gg = *(const float2*)&g[c];
        float2 bb = *(const float2*)&bta[c];
        __hip_bfloat162 ob;
        ob.x = __float2bfloat16((v[j].x - mean)*rs*gg.x + bb.x);
        ob.y = __float2bfloat16((v[j].y - mean)*rs*gg.y + bb.y);
        *(__hip_bfloat162*)&xn[(size_t)l*640 + c] = ob;
    }
}

// ---------------------------------------------------------------------------
// MFMA bf16 GEMM, 128xBN tile, BK=32, 256 threads (4 waves, 2x2 wave grid,
// wave tile 64 x BN/2). A: MxK row-major bf16. Bt: NxK row-major bf16.
// EPI=0: C fp32 store. EPI=1: +aux(seq) residual, scatter to output layout.
// EPI=2: softplus(acc + aux[col]) -> C (dt).
// ---------------------------------------------------------------------------
template<int EPI, int BN>
__global__ __launch_bounds__(256) void gemm_mfma(const __hip_bfloat16* __restrict__ A,
        const __hip_bfloat16* __restrict__ Bt, float* __restrict__ C,
        const float* __restrict__ aux, float* __restrict__ outp, int N, int K)
{
    constexpr int NF = BN/32;        // b-frags per wave
    __shared__ __align__(16) short As[128*32];
    __shared__ __align__(16) short Bs[BN*32];
    int tid = threadIdx.x;
    int lane = tid & 63, wid = tid >> 6;
    int bn0 = blockIdx.x*BN, bm0 = blockIdx.y*128;
    int wm = wid >> 1, wn = wid & 1;
    int fr = lane & 15, ko = (lane >> 4) << 3;
    f32x4 acc[4][NF];
    #pragma unroll
    for (int m = 0; m < 4; ++m)
    #pragma unroll
    for (int n = 0; n < NF; ++n)
        acc[m][n] = (f32x4){0.f, 0.f, 0.f, 0.f};

    for (int k0 = 0; k0 < K; k0 += 32){
        #pragma unroll
        for (int i = 0; i < 2; ++i){
            int c = tid + 256*i;
            int row = c >> 2, kq = (c & 3) << 3;
            gload16(&A[(size_t)(bm0 + row)*K + k0 + kq], (char*)As + c*16);
        }
        #pragma unroll
        for (int i = 0; i < BN/64; ++i){
            int c = tid + 256*i;
            int row = c >> 2, kq = (c & 3) << 3;
            gload16(&Bt[(size_t)(bn0 + row)*K + k0 + kq], (char*)Bs + c*16);
        }
        __syncthreads();
        short8v a[4], b[NF];
        #pragma unroll
        for (int m = 0; m < 4; ++m) a[m] = *(const short8v*)&As[(wm*64 + m*16 + fr)*32 + ko];
        #pragma unroll
        for (int n = 0; n < NF; ++n) b[n] = *(const short8v*)&Bs[(wn*(BN/2) + n*16 + fr)*32 + ko];
        #pragma unroll
        for (int m = 0; m < 4; ++m)
        #pragma unroll
        for (int n = 0; n < NF; ++n)
            acc[m][n] = __builtin_amdgcn_mfma_f32_16x16x32_bf16(a[m], b[n], acc[m][n], 0, 0, 0);
        __syncthreads();
    }

    int rq = (lane >> 4) * 4;
    #pragma unroll
    for (int m = 0; m < 4; ++m){
        #pragma unroll
        for (int r = 0; r < 4; ++r){
            int row = bm0 + wm*64 + m*16 + rq + r;
            if (EPI == 1){
                int hh = row / 96, w2 = row - hh*96;
                int obase = (w2 < 48) ? (hh*48 + w2) : (OUT_HALF + hh*48 + w2 - 48);
                #pragma unroll
                for (int n = 0; n < NF; ++n){
                    int col = bn0 + wn*(BN/2) + n*16 + fr;
                    float v = acc[m][n][r] + aux[(size_t)row*N + col];
                    outp[obase + (size_t)col*2304] = v;
                }
            } else {
                #pragma unroll
                for (int n = 0; n < NF; ++n){
                    int col = bn0 + wn*(BN/2) + n*16 + fr;
                    float v = acc[m][n][r];
                    if (EPI == 2){
                        v += aux[col];
                        v = (v > 20.f) ? v : log1pf(__expf(v));
                    }
                    C[(size_t)row*N + col] = v;
                }
            }
        }
    }
}

// ---------------------------------------------------------------------------
// xproj via MFMA: M=4608, N=64 (56 padded), K=1280. Tile 128x64, 4 waves
// as 4x1 (wave tile 32x64). Writes proj fp32 (L,56) and projb bf16 (L,64)
// with cols >= 40 zeroed (dt-GEMM A-operand).
// ---------------------------------------------------------------------------
__global__ __launch_bounds__(256) void xproj_mfma(const __hip_bfloat16* __restrict__ A,
        const __hip_bfloat16* __restrict__ Bt, float* __restrict__ proj,
        __hip_bfloat16* __restrict__ projb)
{
    __shared__ __align__(16) short As[128*32];
    __shared__ __align__(16) short Bs[64*32];
    int tid = threadIdx.x;
    int lane = tid & 63, wid = tid >> 6;
    int bm0 = blockIdx.x*128;
    int fr = lane & 15, ko = (lane >> 4) << 3;
    f32x4 acc[2][4];
    #pragma unroll
    for (int m = 0; m < 2; ++m)
    #pragma unroll
    for (int n = 0; n < 4; ++n)
        acc[m][n] = (f32x4){0.f, 0.f, 0.f, 0.f};

    for (int k0 = 0; k0 < 1280; k0 += 32){
        #pragma unroll
        for (int i = 0; i < 2; ++i){
            int c = tid + 256*i;
            int row = c >> 2, kq = (c & 3) << 3;
            gload16(&A[(size_t)(bm0 + row)*1280 + k0 + kq], (char*)As + c*16);
        }
        {
            int c = tid;
            int row = c >> 2, kq = (c & 3) << 3;
            gload16(&Bt[(size_t)row*1280 + k0 + kq], (char*)Bs + c*16);
        }
        __syncthreads();
        short8v a[2], b[4];
        #pragma unroll
        for (int m = 0; m < 2; ++m) a[m] = *(const short8v*)&As[(wid*32 + m*16 + fr)*32 + ko];
        #pragma unroll
        for (int n = 0; n < 4; ++n) b[n] = *(const short8v*)&Bs[(n*16 + fr)*32 + ko];
        #pragma unroll
        for (int m = 0; m < 2; ++m)
        #pragma unroll
        for (int n = 0; n < 4; ++n)
            acc[m][n] = __builtin_amdgcn_mfma_f32_16x16x32_bf16(a[m], b[n], acc[m][n], 0, 0, 0);
        __syncthreads();
    }
    int rq = (lane >> 4) * 4;
    #pragma unroll
    for (int m = 0; m < 2; ++m)
    #pragma unroll
    for (int r = 0; r < 4; ++r){
        int row = bm0 + wid*32 + m*16 + rq + r;
        #pragma unroll
        for (int n = 0; n < 4; ++n){
            int col = n*16 + fr;
            float v = acc[m][n][r];
            if (col < 56) proj[row*56 + col] = v;
            projb[row*64 + col] = __float2bfloat16(col < 40 ? v : 0.f);
        }
    }
}

// ---------------------------------------------------------------------------
// Depthwise causal conv (K=4, pad-left 3) + SiLU. Writes fp32 + bf16.
// ---------------------------------------------------------------------------
__global__ __launch_bounds__(256) void k_conv(const float* __restrict__ xz, const float* __restrict__ cw,
        float* __restrict__ xa, __hip_bfloat16* __restrict__ xab)
{
    int gid = blockIdx.x*256 + threadIdx.x;      // < 4608*1280
    int l = gid / 1280, d = gid - l*1280;
    float4 w = *(const float4*)&cw[d*4];
    float acc = w.w * xz[l*2560 + d];
    if (l >= 1) acc = fmaf(w.z, xz[(l-1)*2560 + d], acc);
    if (l >= 2) acc = fmaf(w.y, xz[(l-2)*2560 + d], acc);
    if (l >= 3) acc = fmaf(w.x, xz[(l-3)*2560 + d], acc);
    float v = silu_f(acc);
    xa[gid] = v;
    xab[gid] = __float2bfloat16(v);
}

// ---------------------------------------------------------------------------
// SSM chunked scan (192 chunks x 24).
// ---------------------------------------------------------------------------
__global__ __launch_bounds__(256) void k_scan1(const float* __restrict__ dt, const float* __restrict__ xa,
        const float* __restrict__ proj, const float* __restrict__ A_log,
        float* __restrict__ Hc, float* __restrict__ Sdt)
{
    __shared__ float Bsh[CLEN*8];
    int tid = threadIdx.x;
    int c = blockIdx.x;
    int d = blockIdx.y*256 + tid;
    if (tid < CLEN*8){
        int ll = tid >> 3, s = tid & 7;
        Bsh[tid] = proj[(c*CLEN + ll)*56 + 40 + s];
    }
    float As[8];
    #pragma unroll
    for (int s = 0; s < 8; ++s) As[s] = -__expf(A_log[d*8 + s]);
    __syncthreads();
    float h[8] = {};
    float sdt = 0.f;
    #pragma unroll 4
    for (int ll = 0; ll < CLEN; ++ll){
        int l = c*CLEN + ll;
        float dtv = dt[l*1280 + d];
        float xav = xa[l*1280 + d];
        sdt += dtv;
        float dx = dtv * xav;
        #pragma unroll
        for (int s = 0; s < 8; ++s)
            h[s] = fmaf(__expf(dtv*As[s]), h[s], dx * Bsh[ll*8 + s]);
    }
    int base = (c*1280 + d)*8;
    #pragma unroll
    for (int s = 0; s < 8; ++s) Hc[base + s] = h[s];
    Sdt[c*1280 + d] = sdt;
}

// Inter-chunk scan, parallel over (d,s): 10240 threads, serial over 192 chunks.
__global__ __launch_bounds__(256) void k_scan2(const float* __restrict__ A_log, const float* __restrict__ Hc,
        const float* __restrict__ Sdt, float* __restrict__ Hinit)
{
    int gid = blockIdx.x*256 + threadIdx.x;   // < 10240
    int d = gid >> 3;
    float As = -__expf(A_log[gid]);
    float h = 0.f;
    #pragma unroll 4
    for (int c = 0; c < NCHUNK; ++c){
        Hinit[c*10240 + gid] = h;
        float sdt = Sdt[c*1280 + d];
        h = fmaf(__expf(sdt*As), h, Hc[c*10240 + gid]);
    }
}

__global__ __launch_bounds__(256) void k_scan3(const float* __restrict__ dt, const float* __restrict__ xa,
        const float* __restrict__ proj, const float* __restrict__ xz, const float* __restrict__ A_log,
        const float* __restrict__ Dp, const float* __restrict__ Hinit, __hip_bfloat16* __restrict__ yo)
{
    __shared__ float Bsh[CLEN*8];
    __shared__ float Csh[CLEN*8];
    int tid = threadIdx.x;
    int c = blockIdx.x;
    int d = blockIdx.y*256 + tid;
    if (tid < CLEN*8){
        int ll = tid >> 3, s = tid & 7;
        Bsh[tid] = proj[(c*CLEN + ll)*56 + 40 + s];
        Csh[tid] = proj[(c*CLEN + ll)*56 + 48 + s];
    }
    float As[8];
    #pragma unroll
    for (int s = 0; s < 8; ++s) As[s] = -__expf(A_log[d*8 + s]);
    float Dpv = Dp[d];
    __syncthreads();
    float h[8];
    int hbase = (c*1280 + d)*8;
    #pragma unroll
    for (int s = 0; s < 8; ++s) h[s] = Hinit[hbase + s];
    #pragma unroll 4
    for (int ll = 0; ll < CLEN; ++ll){
        int l = c*CLEN + ll;
        float dtv = dt[l*1280 + d];
        float xav = xa[l*1280 + d];
        float dx = dtv * xav;
        float yv = 0.f;
        #pragma unroll
        for (int s = 0; s < 8; ++s){
            h[s] = fmaf(__expf(dtv*As[s]), h[s], dx * Bsh[ll*8 + s]);
            yv = fmaf(h[s], Csh[ll*8 + s], yv);
        }
        yv = fmaf(xav, Dpv, yv);
        float zv = xz[l*2560 + 1280 + d];
        yo[l*1280 + d] = __float2bfloat16(yv * silu_f(zv));
    }
}

// ---------------------------------------------------------------------------
extern "C" void kernel_launch(void* const* d_in, const int* in_sizes, int n_in,
                              void* d_out, int out_size, void* d_ws, size_t ws_size,
                              hipStream_t stream) {
    const float* x       = (const float*)d_in[0];
    const float* y       = (const float*)d_in[1];
    const float* ln_g    = (const float*)d_in[2];
    const float* ln_b    = (const float*)d_in[3];
    const float* W_in    = (const float*)d_in[4];
    const float* conv_w  = (const float*)d_in[5];
    const float* W_xproj = (const float*)d_in[6];
    const float* W_dt    = (const float*)d_in[7];
    const float* dt_bias = (const float*)d_in[8];
    const float* A_log   = (const float*)d_in[9];
    const float* Dp      = (const float*)d_in[10];
    const float* W_out   = (const float*)d_in[11];
    float* out = (float*)d_out;
    char* w = (char*)d_ws;

    // workspace layout (bytes)
    float* seq   = (float*)(w);                      // 11,796,480
    float* xz    = (float*)(w + 11796480);           // 47,185,920
    float* xa    = (float*)(w + 58982400);           // 23,592,960
    float* proj  = (float*)(w + 82575360);           //  1,032,192
    float* dt    = (float*)(w + 83607552);           // 23,592,960
    float* Hc    = (float*)(w + 107200512);          //  7,864,320
    float* Sdt   = (float*)(w + 115064832);          //    983,040
    float* Hinit = (float*)(w + 116047872);          //  7,864,320
    __hip_bfloat16* xnb   = (__hip_bfloat16*)(w + 123912192);  //  5,898,240
    __hip_bfloat16* xab   = (__hip_bfloat16*)(w + 129810432);  // 11,796,480
    __hip_bfloat16* yob   = (__hip_bfloat16*)(w + 141606912);  // 11,796,480
    __hip_bfloat16* WtIn  = (__hip_bfloat16*)(w + 153403392);  //  3,276,800
    __hip_bfloat16* WtOut = (__hip_bfloat16*)(w + 156680192);  //  1,638,400
    __hip_bfloat16* WtXp  = (__hip_bfloat16*)(w + 158318592);  //    163,840
    __hip_bfloat16* projb = (__hip_bfloat16*)(w + 158482432);  //    589,824
    __hip_bfloat16* Wdtb  = (__hip_bfloat16*)(w + 159072256);  //    163,840  (total ~159.2 MB)

    // Per-call weight transposes (inputs are restored each launch)
    k_transpose<<<dim3(80, 20), 256, 0, stream>>>(W_in,    WtIn,  640, 2560, 2560, 640);
    k_transpose<<<dim3(20, 40), 256, 0, stream>>>(W_out,   WtOut, 1280, 640, 640, 1280);
    k_transpose<<<dim3(2,  40), 256, 0, stream>>>(W_xproj, WtXp,  1280, 56,  64, 1280);
    k_transpose<<<dim3(40,  2), 256, 0, stream>>>(W_dt,    Wdtb,  40, 1280, 1280, 64);

    k_gather<<<dim3(144, 20), 256, 0, stream>>>(x, y, seq);
    k_ln<<<LSEQ, 64, 0, stream>>>(seq, ln_g, ln_b, xnb);
    gemm_mfma<0,128><<<dim3(20, 36), 256, 0, stream>>>(xnb, WtIn, xz, nullptr, nullptr, 2560, 640);
    k_conv<<<(LSEQ*DIN)/256, 256, 0, stream>>>(xz, conv_w, xa, xab);
    xproj_mfma<<<36, 256, 0, stream>>>(xab, WtXp, proj, projb);
    gemm_mfma<2,128><<<dim3(10, 36), 256, 0, stream>>>(projb, Wdtb, dt, dt_bias, nullptr, 1280, 64);
    k_scan1<<<dim3(NCHUNK, 5), 256, 0, stream>>>(dt, xa, proj, A_log, Hc, Sdt);
    k_scan2<<<40, 256, 0, stream>>>(A_log, Hc, Sdt, Hinit);
    k_scan3<<<dim3(NCHUNK, 5), 256, 0, stream>>>(dt, xa, proj, xz, A_log, Dp, Hinit, yob);
    gemm_mfma<1,64><<<dim3(10, 36), 256, 0, stream>>>(yob, WtOut, nullptr, seq, out, 640, 1280);
}

// Round 6
// 318.112 us; speedup vs baseline: 2.2297x; 1.0169x over previous
//
#include <hip/hip_runtime.h>
#include <hip/hip_bf16.h>
#include <math.h>

// Problem constants
#define LSEQ 4608     // 48 * 96
#define CDIM 640
#define DIN 1280
#define DSTATE 8
#define DTRANK 40
#define NCHUNK 192
#define CLEN 24
#define OUT_HALF 1474560  // 640*48*48

typedef __attribute__((ext_vector_type(8))) short short8v;   // 8 bf16 = 4 VGPRs
typedef __attribute__((ext_vector_type(4))) float f32x4;

__device__ __forceinline__ float silu_f(float v){ return v / (1.f + __expf(-v)); }

__device__ __forceinline__ void gload16(const void* g, void* l){
    __builtin_amdgcn_global_load_lds((const __attribute__((address_space(1))) void*)g,
                                     (__attribute__((address_space(3))) void*)l, 16, 0, 0);
}

// ---------------------------------------------------------------------------
// All 4 weight pad-transposes (+fp32->bf16 cast) in ONE launch. Flat grid:
//  [0,1600)   W_in   (640x2560)  -> WtIn  (2560x640),  nbx=80
//  [1600,2400) W_out (1280x640)  -> WtOut (640x1280),  nbx=20
//  [2400,2480) W_xp  (1280x56)   -> WtXp  (64x1280),   nbx=2
//  [2480,2560) W_dt  (40x1280)   -> Wdtb  (1280x64),   nbx=40
// ---------------------------------------------------------------------------
__global__ __launch_bounds__(256) void k_transpose_all(
        const float* __restrict__ W_in, const float* __restrict__ W_out,
        const float* __restrict__ W_xp, const float* __restrict__ W_dt,
        __hip_bfloat16* __restrict__ WtIn, __hip_bfloat16* __restrict__ WtOut,
        __hip_bfloat16* __restrict__ WtXp, __hip_bfloat16* __restrict__ Wdtb)
{
    __shared__ float t[32][33];
    int b = blockIdx.x;
    const float* in; __hip_bfloat16* out; int R, C, Cp, Rp, nbx;
    if (b < 1600)      { in = W_in;  out = WtIn;  R = 640;  C = 2560; Cp = 2560; Rp = 640;  nbx = 80; }
    else if (b < 2400) { b -= 1600; in = W_out; out = WtOut; R = 1280; C = 640;  Cp = 640;  Rp = 1280; nbx = 20; }
    else if (b < 2480) { b -= 2400; in = W_xp;  out = WtXp;  R = 1280; C = 56;   Cp = 64;   Rp = 1280; nbx = 2; }
    else               { b -= 2480; in = W_dt;  out = Wdtb;  R = 40;   C = 1280; Cp = 1280; Rp = 64;   nbx = 40; }
    int bx = b % nbx, by = b / nbx;
    int tid = threadIdx.x;
    int tx = tid & 31, ty = tid >> 5;
    int r0 = by*32, c0 = bx*32;
    #pragma unroll
    for (int i = 0; i < 4; ++i){
        int r = r0 + ty + i*8, c = c0 + tx;
        t[ty + i*8][tx] = (r < R && c < C) ? in[(size_t)r*C + c] : 0.f;
    }
    __syncthreads();
    #pragma unroll
    for (int i = 0; i < 4; ++i){
        int c = c0 + ty + i*8;
        out[(size_t)c*Rp + r0 + tx] = __float2bfloat16(t[tx][ty + i*8]);
    }
}

// ---------------------------------------------------------------------------
// Gather/transpose x,y (C,48,48 each) -> seq (L=4608, 640) fp32. Grid (144,20).
// ---------------------------------------------------------------------------
__global__ __launch_bounds__(256) void k_gather(const float* __restrict__ x,
        const float* __restrict__ y, float* __restrict__ seq)
{
    __shared__ float t[32][33];
    int tid = threadIdx.x;
    int tx = tid & 31, ty = tid >> 5;
    int l0 = blockIdx.x*32, c0 = blockIdx.y*32;
    int l = l0 + tx;
    int h = l / 96, w2 = l - h*96;
    const float* src = (w2 < 48) ? x : y;
    int col = h*48 + (w2 < 48 ? w2 : w2 - 48);
    #pragma unroll
    for (int i = 0; i < 4; ++i)
        t[tx][ty + i*8] = src[(size_t)(c0 + ty + i*8)*2304 + col];
    __syncthreads();
    #pragma unroll
    for (int i = 0; i < 4; ++i){
        int l2 = l0 + ty + i*8;
        seq[(size_t)l2*640 + c0 + tx] = t[ty + i*8][tx];
    }
}

// ---------------------------------------------------------------------------
// Row LayerNorm: seq (L,640) fp32 -> xn (L,640) bf16. 1 wave per row.
// ---------------------------------------------------------------------------
__global__ __launch_bounds__(64) void k_ln(const float* __restrict__ seq,
        const float* __restrict__ g, const float* __restrict__ bta,
        __hip_bfloat16* __restrict__ xn)
{
    int l = blockIdx.x;
    int lane = threadIdx.x;
    const float* row = seq + (size_t)l*640;
    float2 v[5];
    float s = 0.f, s2 = 0.f;
    #pragma unroll
    for (int j = 0; j < 5; ++j){
        v[j] = *(const float2*)&row[j*128 + lane*2];
        s  += v[j].x + v[j].y;
        s2 += v[j].x*v[j].x + v[j].y*v[j].y;
    }
    #pragma unroll
    for (int off = 32; off > 0; off >>= 1){
        s  += __shfl_xor(s,  off, 64);
        s2 += __shfl_xor(s2, off, 64);
    }
    float mean = s * (1.f/640.f);
    float rs = rsqrtf(s2 * (1.f/640.f) - mean*mean + 1e-5f);
    #pragma unroll
    for (int j = 0; j < 5; ++j){
        int c = j*128 + lane*2;
        float2 gg = *(const float2*)&g[c];
        float2 bb = *(const float2*)&bta[c];
        __hip_bfloat162 ob;
        ob.x = __float2bfloat16((v[j].x - mean)*rs*gg.x + bb.x);
        ob.y = __float2bfloat16((v[j].y - mean)*rs*gg.y + bb.y);
        *(__hip_bfloat162*)&xn[(size_t)l*640 + c] = ob;
    }
}

// ---------------------------------------------------------------------------
// MFMA bf16 GEMM, 128xBN tile, BK=32, 256 threads (4 waves, 2x2 wave grid,
// wave tile 64 x BN/2). A: MxK row-major bf16. Bt: NxK row-major bf16.
// EPI=0: bf16 store to Cb. EPI=1: +aux(seq) residual fp32, scatter to output.
// EPI=2: softplus(acc + aux[col]) -> bf16 Cb (dt).
// ---------------------------------------------------------------------------
template<int EPI, int BN>
__global__ __launch_bounds__(256) void gemm_mfma(const __hip_bfloat16* __restrict__ A,
        const __hip_bfloat16* __restrict__ Bt, __hip_bfloat16* __restrict__ Cb,
        const float* __restrict__ aux, float* __restrict__ outp, int N, int K)
{
    constexpr int NF = BN/32;        // b-frags per wave
    __shared__ __align__(16) short As[128*32];
    __shared__ __align__(16) short Bs[BN*32];
    int tid = threadIdx.x;
    int lane = tid & 63, wid = tid >> 6;
    int bn0 = blockIdx.x*BN, bm0 = blockIdx.y*128;
    int wm = wid >> 1, wn = wid & 1;
    int fr = lane & 15, ko = (lane >> 4) << 3;
    f32x4 acc[4][NF];
    #pragma unroll
    for (int m = 0; m < 4; ++m)
    #pragma unroll
    for (int n = 0; n < NF; ++n)
        acc[m][n] = (f32x4){0.f, 0.f, 0.f, 0.f};

    for (int k0 = 0; k0 < K; k0 += 32){
        #pragma unroll
        for (int i = 0; i < 2; ++i){
            int c = tid + 256*i;
            int row = c >> 2, kq = (c & 3) << 3;
            gload16(&A[(size_t)(bm0 + row)*K + k0 + kq], (char*)As + c*16);
        }
        #pragma unroll
        for (int i = 0; i < BN/64; ++i){
            int c = tid + 256*i;
            int row = c >> 2, kq = (c & 3) << 3;
            gload16(&Bt[(size_t)(bn0 + row)*K + k0 + kq], (char*)Bs + c*16);
        }
        __syncthreads();
        short8v a[4], b[NF];
        #pragma unroll
        for (int m = 0; m < 4; ++m) a[m] = *(const short8v*)&As[(wm*64 + m*16 + fr)*32 + ko];
        #pragma unroll
        for (int n = 0; n < NF; ++n) b[n] = *(const short8v*)&Bs[(wn*(BN/2) + n*16 + fr)*32 + ko];
        #pragma unroll
        for (int m = 0; m < 4; ++m)
        #pragma unroll
        for (int n = 0; n < NF; ++n)
            acc[m][n] = __builtin_amdgcn_mfma_f32_16x16x32_bf16(a[m], b[n], acc[m][n], 0, 0, 0);
        __syncthreads();
    }

    int rq = (lane >> 4) * 4;
    #pragma unroll
    for (int m = 0; m < 4; ++m){
        #pragma unroll
        for (int r = 0; r < 4; ++r){
            int row = bm0 + wm*64 + m*16 + rq + r;
            if (EPI == 1){
                int hh = row / 96, w2 = row - hh*96;
                int obase = (w2 < 48) ? (hh*48 + w2) : (OUT_HALF + hh*48 + w2 - 48);
                #pragma unroll
                for (int n = 0; n < NF; ++n){
                    int col = bn0 + wn*(BN/2) + n*16 + fr;
                    float v = acc[m][n][r] + aux[(size_t)row*N + col];
                    outp[obase + (size_t)col*2304] = v;
                }
            } else {
                #pragma unroll
                for (int n = 0; n < NF; ++n){
                    int col = bn0 + wn*(BN/2) + n*16 + fr;
                    float v = acc[m][n][r];
                    if (EPI == 2){
                        v += aux[col];
                        v = (v > 20.f) ? v : log1pf(__expf(v));
                    }
                    Cb[(size_t)row*N + col] = __float2bfloat16(v);
                }
            }
        }
    }
}

// ---------------------------------------------------------------------------
// xproj via MFMA: M=4608, N=64 (56 padded), K=1280. Tile 128x64, 4 waves
// as 4x1 (wave tile 32x64). Writes proj fp32 (L,56) and projb bf16 (L,64)
// with cols >= 40 zeroed (dt-GEMM A-operand).
// ---------------------------------------------------------------------------
__global__ __launch_bounds__(256) void xproj_mfma(const __hip_bfloat16* __restrict__ A,
        const __hip_bfloat16* __restrict__ Bt, float* __restrict__ proj,
        __hip_bfloat16* __restrict__ projb)
{
    __shared__ __align__(16) short As[128*32];
    __shared__ __align__(16) short Bs[64*32];
    int tid = threadIdx.x;
    int lane = tid & 63, wid = tid >> 6;
    int bm0 = blockIdx.x*128;
    int fr = lane & 15, ko = (lane >> 4) << 3;
    f32x4 acc[2][4];
    #pragma unroll
    for (int m = 0; m < 2; ++m)
    #pragma unroll
    for (int n = 0; n < 4; ++n)
        acc[m][n] = (f32x4){0.f, 0.f, 0.f, 0.f};

    for (int k0 = 0; k0 < 1280; k0 += 32){
        #pragma unroll
        for (int i = 0; i < 2; ++i){
            int c = tid + 256*i;
            int row = c >> 2, kq = (c & 3) << 3;
            gload16(&A[(size_t)(bm0 + row)*1280 + k0 + kq], (char*)As + c*16);
        }
        {
            int c = tid;
            int row = c >> 2, kq = (c & 3) << 3;
            gload16(&Bt[(size_t)row*1280 + k0 + kq], (char*)Bs + c*16);
        }
        __syncthreads();
        short8v a[2], b[4];
        #pragma unroll
        for (int m = 0; m < 2; ++m) a[m] = *(const short8v*)&As[(wid*32 + m*16 + fr)*32 + ko];
        #pragma unroll
        for (int n = 0; n < 4; ++n) b[n] = *(const short8v*)&Bs[(n*16 + fr)*32 + ko];
        #pragma unroll
        for (int m = 0; m < 2; ++m)
        #pragma unroll
        for (int n = 0; n < 4; ++n)
            acc[m][n] = __builtin_amdgcn_mfma_f32_16x16x32_bf16(a[m], b[n], acc[m][n], 0, 0, 0);
        __syncthreads();
    }
    int rq = (lane >> 4) * 4;
    #pragma unroll
    for (int m = 0; m < 2; ++m)
    #pragma unroll
    for (int r = 0; r < 4; ++r){
        int row = bm0 + wid*32 + m*16 + rq + r;
        #pragma unroll
        for (int n = 0; n < 4; ++n){
            int col = n*16 + fr;
            float v = acc[m][n][r];
            if (col < 56) proj[row*56 + col] = v;
            projb[row*64 + col] = __float2bfloat16(col < 40 ? v : 0.f);
        }
    }
}

// ---------------------------------------------------------------------------
// Depthwise causal conv (K=4, pad-left 3) + SiLU. bf16 in (xzb xp-half,
// row stride 2560), bf16 out. 2 channels per thread via bfloat162.
// ---------------------------------------------------------------------------
__global__ __launch_bounds__(256) void k_conv(const __hip_bfloat16* __restrict__ xzb,
        const float* __restrict__ cw, __hip_bfloat16* __restrict__ xab)
{
    int gid = blockIdx.x*256 + threadIdx.x;      // < 4608*640
    int l = gid / 640, dp = gid - l*640;
    int d = dp*2;
    float4 w0 = *(const float4*)&cw[d*4];
    float4 w1 = *(const float4*)&cw[d*4 + 4];
    __hip_bfloat162 v = *(const __hip_bfloat162*)&xzb[(size_t)l*2560 + d];
    float a0 = w0.w * __bfloat162float(v.x);
    float a1 = w1.w * __bfloat162float(v.y);
    if (l >= 1){
        v = *(const __hip_bfloat162*)&xzb[(size_t)(l-1)*2560 + d];
        a0 = fmaf(w0.z, __bfloat162float(v.x), a0);
        a1 = fmaf(w1.z, __bfloat162float(v.y), a1);
    }
    if (l >= 2){
        v = *(const __hip_bfloat162*)&xzb[(size_t)(l-2)*2560 + d];
        a0 = fmaf(w0.y, __bfloat162float(v.x), a0);
        a1 = fmaf(w1.y, __bfloat162float(v.y), a1);
    }
    if (l >= 3){
        v = *(const __hip_bfloat162*)&xzb[(size_t)(l-3)*2560 + d];
        a0 = fmaf(w0.x, __bfloat162float(v.x), a0);
        a1 = fmaf(w1.x, __bfloat162float(v.y), a1);
    }
    __hip_bfloat162 o;
    o.x = __float2bfloat16(silu_f(a0));
    o.y = __float2bfloat16(silu_f(a1));
    *(__hip_bfloat162*)&xab[(size_t)l*1280 + d] = o;
}

// ---------------------------------------------------------------------------
// SSM chunked scan (192 chunks x 24). Block 128 threads, 2 d-channels/thread.
// ---------------------------------------------------------------------------
__global__ __launch_bounds__(128) void k_scan1(const __hip_bfloat16* __restrict__ dtb,
        const __hip_bfloat16* __restrict__ xab, const float* __restrict__ proj,
        const float* __restrict__ A_log, float* __restrict__ Hc, float* __restrict__ Sdt)
{
    __shared__ float Bsh[CLEN*8];
    int tid = threadIdx.x;
    int c = blockIdx.x;
    int d = blockIdx.y*256 + tid*2;
    for (int i = tid; i < CLEN*8; i += 128){
        int ll = i >> 3, s = i & 7;
        Bsh[i] = proj[(c*CLEN + ll)*56 + 40 + s];
    }
    float As0[8], As1[8];
    #pragma unroll
    for (int s = 0; s < 8; ++s){
        As0[s] = -__expf(A_log[d*8 + s]);
        As1[s] = -__expf(A_log[d*8 + 8 + s]);
    }
    __syncthreads();
    float h0[8] = {}, h1[8] = {};
    float sdt0 = 0.f, sdt1 = 0.f;
    #pragma unroll 4
    for (int ll = 0; ll < CLEN; ++ll){
        int l = c*CLEN + ll;
        __hip_bfloat162 dt2 = *(const __hip_bfloat162*)&dtb[(size_t)l*1280 + d];
        __hip_bfloat162 xa2 = *(const __hip_bfloat162*)&xab[(size_t)l*1280 + d];
        float dtv0 = __bfloat162float(dt2.x), dtv1 = __bfloat162float(dt2.y);
        float dx0 = dtv0 * __bfloat162float(xa2.x);
        float dx1 = dtv1 * __bfloat162float(xa2.y);
        sdt0 += dtv0; sdt1 += dtv1;
        #pragma unroll
        for (int s = 0; s < 8; ++s){
            float bb = Bsh[ll*8 + s];
            h0[s] = fmaf(__expf(dtv0*As0[s]), h0[s], dx0 * bb);
            h1[s] = fmaf(__expf(dtv1*As1[s]), h1[s], dx1 * bb);
        }
    }
    size_t base = ((size_t)c*1280 + d)*8;
    *(float4*)&Hc[base     ] = make_float4(h0[0], h0[1], h0[2], h0[3]);
    *(float4*)&Hc[base + 4 ] = make_float4(h0[4], h0[5], h0[6], h0[7]);
    *(float4*)&Hc[base + 8 ] = make_float4(h1[0], h1[1], h1[2], h1[3]);
    *(float4*)&Hc[base + 12] = make_float4(h1[4], h1[5], h1[6], h1[7]);
    Sdt[c*1280 + d] = sdt0;
    Sdt[c*1280 + d + 1] = sdt1;
}

// Inter-chunk scan, parallel over (d,s): 10240 threads, serial over 192 chunks.
__global__ __launch_bounds__(256) void k_scan2(const float* __restrict__ A_log, const float* __restrict__ Hc,
        const float* __restrict__ Sdt, float* __restrict__ Hinit)
{
    int gid = blockIdx.x*256 + threadIdx.x;   // < 10240
    int d = gid >> 3;
    float As = -__expf(A_log[gid]);
    float h = 0.f;
    #pragma unroll 4
    for (int c = 0; c < NCHUNK; ++c){
        Hinit[c*10240 + gid] = h;
        float sdt = Sdt[c*1280 + d];
        h = fmaf(__expf(sdt*As), h, Hc[c*10240 + gid]);
    }
}

__global__ __launch_bounds__(128) void k_scan3(const __hip_bfloat16* __restrict__ dtb,
        const __hip_bfloat16* __restrict__ xab, const float* __restrict__ proj,
        const __hip_bfloat16* __restrict__ xzb, const float* __restrict__ A_log,
        const float* __restrict__ Dp, const float* __restrict__ Hinit,
        __hip_bfloat16* __restrict__ yo)
{
    __shared__ float Bsh[CLEN*8];
    __shared__ float Csh[CLEN*8];
    int tid = threadIdx.x;
    int c = blockIdx.x;
    int d = blockIdx.y*256 + tid*2;
    for (int i = tid; i < CLEN*8; i += 128){
        int ll = i >> 3, s = i & 7;
        Bsh[i] = proj[(c*CLEN + ll)*56 + 40 + s];
        Csh[i] = proj[(c*CLEN + ll)*56 + 48 + s];
    }
    float As0[8], As1[8];
    #pragma unroll
    for (int s = 0; s < 8; ++s){
        As0[s] = -__expf(A_log[d*8 + s]);
        As1[s] = -__expf(A_log[d*8 + 8 + s]);
    }
    float Dp0 = Dp[d], Dp1 = Dp[d + 1];
    __syncthreads();
    float h0[8], h1[8];
    size_t base = ((size_t)c*1280 + d)*8;
    {
        float4 t0 = *(const float4*)&Hinit[base];
        float4 t1 = *(const float4*)&Hinit[base + 4];
        float4 t2 = *(const float4*)&Hinit[base + 8];
        float4 t3 = *(const float4*)&Hinit[base + 12];
        h0[0]=t0.x; h0[1]=t0.y; h0[2]=t0.z; h0[3]=t0.w;
        h0[4]=t1.x; h0[5]=t1.y; h0[6]=t1.z; h0[7]=t1.w;
        h1[0]=t2.x; h1[1]=t2.y; h1[2]=t2.z; h1[3]=t2.w;
        h1[4]=t3.x; h1[5]=t3.y; h1[6]=t3.z; h1[7]=t3.w;
    }
    #pragma unroll 4
    for (int ll = 0; ll < CLEN; ++ll){
        int l = c*CLEN + ll;
        __hip_bfloat162 dt2 = *(const __hip_bfloat162*)&dtb[(size_t)l*1280 + d];
        __hip_bfloat162 xa2 = *(const __hip_bfloat162*)&xab[(size_t)l*1280 + d];
        __hip_bfloat162 z2  = *(const __hip_bfloat162*)&xzb[(size_t)l*2560 + 1280 + d];
        float dtv0 = __bfloat162float(dt2.x), dtv1 = __bfloat162float(dt2.y);
        float xav0 = __bfloat162float(xa2.x), xav1 = __bfloat162float(xa2.y);
        float dx0 = dtv0 * xav0, dx1 = dtv1 * xav1;
        float yv0 = 0.f, yv1 = 0.f;
        #pragma unroll
        for (int s = 0; s < 8; ++s){
            float bb = Bsh[ll*8 + s];
            float cc = Csh[ll*8 + s];
            h0[s] = fmaf(__expf(dtv0*As0[s]), h0[s], dx0 * bb);
            h1[s] = fmaf(__expf(dtv1*As1[s]), h1[s], dx1 * bb);
            yv0 = fmaf(h0[s], cc, yv0);
            yv1 = fmaf(h1[s], cc, yv1);
        }
        yv0 = fmaf(xav0, Dp0, yv0);
        yv1 = fmaf(xav1, Dp1, yv1);
        yv0 *= silu_f(__bfloat162float(z2.x));
        yv1 *= silu_f(__bfloat162float(z2.y));
        __hip_bfloat162 o;
        o.x = __float2bfloat16(yv0);
        o.y = __float2bfloat16(yv1);
        *(__hip_bfloat162*)&yo[(size_t)l*1280 + d] = o;
    }
}

// ---------------------------------------------------------------------------
extern "C" void kernel_launch(void* const* d_in, const int* in_sizes, int n_in,
                              void* d_out, int out_size, void* d_ws, size_t ws_size,
                              hipStream_t stream) {
    const float* x       = (const float*)d_in[0];
    const float* y       = (const float*)d_in[1];
    const float* ln_g    = (const float*)d_in[2];
    const float* ln_b    = (const float*)d_in[3];
    const float* W_in    = (const float*)d_in[4];
    const float* conv_w  = (const float*)d_in[5];
    const float* W_xproj = (const float*)d_in[6];
    const float* W_dt    = (const float*)d_in[7];
    const float* dt_bias = (const float*)d_in[8];
    const float* A_log   = (const float*)d_in[9];
    const float* Dp      = (const float*)d_in[10];
    const float* W_out   = (const float*)d_in[11];
    float* out = (float*)d_out;
    char* w = (char*)d_ws;

    // workspace layout (bytes)
    float*          seq   = (float*)(w);                        // 11,796,480
    __hip_bfloat16* xzb   = (__hip_bfloat16*)(w + 11796480);    // 23,592,960
    __hip_bfloat16* xab   = (__hip_bfloat16*)(w + 35389440);    // 11,796,480
    __hip_bfloat16* dtb   = (__hip_bfloat16*)(w + 47185920);    // 11,796,480
    float*          proj  = (float*)(w + 58982400);             //  1,032,192
    __hip_bfloat16* projb = (__hip_bfloat16*)(w + 60014592);    //    589,824
    float*          Hc    = (float*)(w + 60604416);             //  7,864,320
    float*          Sdt   = (float*)(w + 68468736);             //    983,040
    float*          Hinit = (float*)(w + 69451776);             //  7,864,320
    __hip_bfloat16* xnb   = (__hip_bfloat16*)(w + 77316096);    //  5,898,240
    __hip_bfloat16* yob   = (__hip_bfloat16*)(w + 83214336);    // 11,796,480
    __hip_bfloat16* WtIn  = (__hip_bfloat16*)(w + 95010816);    //  3,276,800
    __hip_bfloat16* WtOut = (__hip_bfloat16*)(w + 98287616);    //  1,638,400
    __hip_bfloat16* WtXp  = (__hip_bfloat16*)(w + 99926016);    //    163,840
    __hip_bfloat16* Wdtb  = (__hip_bfloat16*)(w + 100089856);   //    163,840  (total ~100.3 MB)

    k_transpose_all<<<2560, 256, 0, stream>>>(W_in, W_out, W_xproj, W_dt,
                                              WtIn, WtOut, WtXp, Wdtb);
    k_gather<<<dim3(144, 20), 256, 0, stream>>>(x, y, seq);
    k_ln<<<LSEQ, 64, 0, stream>>>(seq, ln_g, ln_b, xnb);
    gemm_mfma<0,128><<<dim3(20, 36), 256, 0, stream>>>(xnb, WtIn, xzb, nullptr, nullptr, 2560, 640);
    k_conv<<<(LSEQ*640)/256, 256, 0, stream>>>(xzb, conv_w, xab);
    xproj_mfma<<<36, 256, 0, stream>>>(xab, WtXp, proj, projb);
    gemm_mfma<2,128><<<dim3(10, 36), 256, 0, stream>>>(projb, Wdtb, dtb, dt_bias, nullptr, 1280, 64);
    k_scan1<<<dim3(NCHUNK, 5), 128, 0, stream>>>(dtb, xab, proj, A_log, Hc, Sdt);
    k_scan2<<<40, 256, 0, stream>>>(A_log, Hc, Sdt, Hinit);
    k_scan3<<<dim3(NCHUNK, 5), 128, 0, stream>>>(dtb, xab, proj, xzb, A_log, Dp, Hinit, yob);
    gemm_mfma<1,64><<<dim3(10, 36), 256, 0, stream>>>(yob, WtOut, nullptr, seq, out, 640, 1280);
}